// Round 5
// baseline (226.144 us; speedup 1.0000x reference)
//
#include <hip/hip_runtime.h>
#include <hip/hip_bf16.h>

#define NB 4
#define NS 2048
#define ND 768
#define NH 12
#define NDH 64
#define NM (NB * NS)  // 8192

// fold 1/sqrt(64) * log2(e) into Q so softmax = exp2(s + m)
#define QSCALE 0.1803368867f
#define MSCALE (-1.442695041e9f)

typedef __attribute__((ext_vector_type(8))) short short8;    // 8 x bf16
typedef __attribute__((ext_vector_type(4))) float f32x4;
typedef __attribute__((ext_vector_type(16))) float f32x16;

__device__ __forceinline__ void async_ld16(const void* g, void* l) {
  __builtin_amdgcn_global_load_lds(
      (const __attribute__((address_space(1))) void*)g,
      (__attribute__((address_space(3))) void*)l, 16, 0, 0);
}

// single-instruction pack: lo = bf16(a), hi = bf16(b)
__device__ __forceinline__ unsigned cvt_pk(float a, float b) {
  unsigned r;
  asm("v_cvt_pk_bf16_f32 %0, %1, %2" : "=v"(r) : "v"(a), "v"(b));
  return r;
}

// ---------------- f32 -> bf16 convert (vectorized, 8/thread) --------------
__global__ __launch_bounds__(256) void convert_bf16_kernel(
    const float* __restrict__ in, __hip_bfloat16* __restrict__ out, int n8) {
  const int i = blockIdx.x * 256 + threadIdx.x;
  if (i >= n8) return;
  const float4 a = ((const float4*)in)[i * 2];
  const float4 b = ((const float4*)in)[i * 2 + 1];
  unsigned u[4];
  u[0] = cvt_pk(a.x, a.y);
  u[1] = cvt_pk(a.z, a.w);
  u[2] = cvt_pk(b.x, b.y);
  u[3] = cvt_pk(b.z, b.w);
  ((uint4*)out)[i] = uint4{u[0], u[1], u[2], u[3]};
}

// ------- weight transpose+convert: W[K][N] f32 -> Wt[N][K] bf16 -----------
__global__ __launch_bounds__(256) void transpose_w_kernel(
    const float* __restrict__ w0, const float* __restrict__ w1,
    const float* __restrict__ w2, const float* __restrict__ w3,
    __hip_bfloat16* __restrict__ WtAll) {
  __shared__ __hip_bfloat16 tile[64][66];
  const float* src = blockIdx.z == 0 ? w0 : blockIdx.z == 1 ? w1
                   : blockIdx.z == 2 ? w2 : w3;
  __hip_bfloat16* dst = WtAll + (size_t)blockIdx.z * ND * ND;
  const int kk0 = blockIdx.y * 64, nn0 = blockIdx.x * 64;
  const int t = threadIdx.x;
#pragma unroll
  for (int p = 0; p < 4; ++p) {
    const int idx = p * 256 + t;
    const int k = idx >> 4;
    const int c = (idx & 15) * 4;
    const float4 v = *(const float4*)(src + (size_t)(kk0 + k) * ND + nn0 + c);
    uint* tp = (uint*)&tile[k][c];
    tp[0] = cvt_pk(v.x, v.y);
    tp[1] = cvt_pk(v.z, v.w);
  }
  __syncthreads();
#pragma unroll
  for (int p = 0; p < 2; ++p) {
    const int idx = p * 256 + t;
    const int n = idx >> 3;
    const int kb = (idx & 7) * 8;
    short8 v;
    __hip_bfloat16* pv = (__hip_bfloat16*)&v;
#pragma unroll
    for (int j = 0; j < 8; ++j) pv[j] = tile[kb + j][n];
    *(short8*)(dst + (size_t)(nn0 + n) * ND + kk0 + kb) = v;
  }
}

// ------- fused QKV GEMM: [M,768] @ Wt[2304,768]^T -> Q,K rowmajor + V^T ---
// Q output is pre-scaled by QSCALE (softmax exp2 domain).
__global__ __launch_bounds__(256) void qkv_gemm_kernel(
    const __hip_bfloat16* __restrict__ A,
    const __hip_bfloat16* __restrict__ Bt,
    const float* __restrict__ bq, const float* __restrict__ bk,
    const float* __restrict__ bv,
    __hip_bfloat16* __restrict__ Qw, __hip_bfloat16* __restrict__ Kw,
    __hip_bfloat16* __restrict__ Vt) {
  __shared__ __hip_bfloat16 As[128 * 32];
  __shared__ __hip_bfloat16 Bs[64 * 32];
  const int K = ND;
  const int tid = threadIdx.x;
  const int w = tid >> 6, l = tid & 63;
  const int lk = l & 15, lt = l >> 4;
  const int m0 = blockIdx.y * 128, n0 = blockIdx.x * 64;
  const int wr = w >> 1, wc = w & 1;

  f32x4 acc[4][2] = {};

  const int arow = w * 32 + (l >> 2);
  const int acol = (l & 3) * 8;
  const __hip_bfloat16* aptr = A + (size_t)(m0 + arow) * K + acol;
  const int brow = w * 16 + (l >> 2);
  const __hip_bfloat16* bptr = Bt + (size_t)(n0 + brow) * K + acol;
  __hip_bfloat16* asb = As + w * 1024;
  __hip_bfloat16* bsb = Bs + w * 512;

  for (int k0 = 0; k0 < K; k0 += 32) {
    __syncthreads();
    async_ld16(aptr + k0, asb);
    async_ld16(aptr + (size_t)16 * K + k0, asb + 512);
    async_ld16(bptr + k0, bsb);
    __syncthreads();

    short8 af[4], bf[2];
#pragma unroll
    for (int m = 0; m < 4; ++m)
      af[m] = *(const short8*)(As + (wr * 64 + m * 16 + lk) * 32 + lt * 8);
#pragma unroll
    for (int n = 0; n < 2; ++n)
      bf[n] = *(const short8*)(Bs + (wc * 32 + n * 16 + lk) * 32 + lt * 8);
#pragma unroll
    for (int m = 0; m < 4; ++m)
#pragma unroll
      for (int n = 0; n < 2; ++n)
        acc[m][n] =
            __builtin_amdgcn_mfma_f32_16x16x32_bf16(af[m], bf[n], acc[m][n], 0, 0, 0);
  }

  const int mi = n0 / ND;          // 0=Q, 1=K, 2=V
  const int nbase = n0 - mi * ND;
  const float* bp = mi == 0 ? bq : mi == 1 ? bk : bv;
  const float oscale = (mi == 0) ? QSCALE : 1.f;

#pragma unroll
  for (int n = 0; n < 2; ++n) {
    const int col = nbase + wc * 32 + n * 16 + lk;
    const float bb = bp[col];
#pragma unroll
    for (int m = 0; m < 4; ++m) {
      const int row = m0 + wr * 64 + m * 16 + lt * 4;
#pragma unroll
      for (int r = 0; r < 4; ++r) {
        const float v = (acc[m][n][r] + bb) * oscale;
        if (mi < 2) {
          (mi ? Kw : Qw)[(size_t)(row + r) * ND + col] = __float2bfloat16(v);
        } else {
          const int mrow = row + r;
          const int bidx = mrow >> 11, s = mrow & 2047;
          const int hh = col >> 6, dh = col & 63;
          Vt[(((size_t)bidx * NH + hh) * NDH + dh) * NS + s] = __float2bfloat16(v);
        }
      }
    }
  }
}

// ---------------- MFMA-32x32 flash attention, register-resident P ---------
__global__ __launch_bounds__(256) void mha_mfma32_kernel(
    const __hip_bfloat16* __restrict__ Qb, const __hip_bfloat16* __restrict__ Kb,
    const __hip_bfloat16* __restrict__ Vt, const float* __restrict__ mask,
    __hip_bfloat16* __restrict__ ctx) {
  __shared__ __align__(16) char smem[33280];
  char* KsB = smem;
  char* VsB = smem + 16384;
  float* mperm = (float*)(smem + 32768);

  const int b = blockIdx.z, h = blockIdx.y;
  const int tid = threadIdx.x;
  const int w = tid >> 6, l = tid & 63;
  const int l31 = l & 31, hi = l >> 5;
  const int q0 = blockIdx.x * 128 + w * 32;

  const __hip_bfloat16* qp = Qb + ((size_t)b * NS + q0 + l31) * ND + h * NDH;
  short8 qf[4];
#pragma unroll
  for (int ks = 0; ks < 4; ++ks)
    qf[ks] = *(const short8*)(qp + ks * 16 + hi * 8);

  f32x16 c0 = {}, c1 = {};
  float lpart = 0.f;

  const int srow = l >> 3, slot = l & 7;
  const int key1 = w * 8 + srow, key2 = key1 + 32;
  const __hip_bfloat16* kg1 =
      Kb + ((size_t)b * NS + key1) * ND + h * NDH + (slot ^ (key1 & 7)) * 8;
  const __hip_bfloat16* kg2 =
      Kb + ((size_t)b * NS + key2) * ND + h * NDH + (slot ^ (key2 & 7)) * 8;
  const __hip_bfloat16* vg1 =
      Vt + (((size_t)b * NH + h) * NDH + key1) * NS + (slot ^ (key1 & 7)) * 8;
  const __hip_bfloat16* vg2 =
      Vt + (((size_t)b * NH + h) * NDH + key2) * NS + (slot ^ (key2 & 7)) * 8;
  const int ldsoff = w * 1024;
  const float* mb = mask + (size_t)b * NS;

  const int mg_ = tid >> 5, mhi_ = (tid >> 4) & 1, mr_ = tid & 15;
  const int mkey = mg_ * 32 + 4 * mhi_ + (mr_ & 3) + 8 * (mr_ >> 2);

#define STAGE(buf, t)                                                        \
  {                                                                          \
    const size_t koff = (size_t)(t) * 64 * ND;                               \
    char* kd = KsB + (buf) * 8192 + ldsoff;                                  \
    char* vd = VsB + (buf) * 8192 + ldsoff;                                  \
    async_ld16(kg1 + koff, kd);                                              \
    async_ld16(kg2 + koff, kd + 4096);                                       \
    async_ld16(vg1 + (t) * 64, vd);                                          \
    async_ld16(vg2 + (t) * 64, vd + 4096);                                   \
    if (tid < 64) mperm[(buf) * 64 + tid] = mb[(t) * 64 + mkey] * MSCALE;    \
  }

  STAGE(0, 0);
  const int swz = (l31 & 7) << 4;

  for (int t = 0; t < 32; ++t) {
    __syncthreads();  // stage(t) complete; buf((t+1)&1) free
    if (t + 1 < 32) STAGE((t + 1) & 1, t + 1);
    const int bufo = (t & 1) * 8192;

    // ---- QK^T (setprio: keep matrix pipe fed) ----
    f32x16 s0 = {}, s1 = {};
    __builtin_amdgcn_s_setprio(1);
#pragma unroll
    for (int ks = 0; ks < 4; ++ks) {
      const int off = (((ks << 5) | (hi << 4)) ^ swz);
      const short8 kf0 = *(const short8*)(KsB + bufo + (l31 << 7) + off);
      s0 = __builtin_amdgcn_mfma_f32_32x32x16_bf16(kf0, qf[ks], s0, 0, 0, 0);
      const short8 kf1 = *(const short8*)(KsB + bufo + ((32 + l31) << 7) + off);
      s1 = __builtin_amdgcn_mfma_f32_32x32x16_bf16(kf1, qf[ks], s1, 0, 0, 0);
    }
    __builtin_amdgcn_s_setprio(0);

    // ---- softmax: p = exp2(s + m), native v_exp_f32, no mul/clamp ----
    {
      const f32x4* mv = (const f32x4*)(mperm + (t & 1) * 64 + hi * 16);
#pragma unroll
      for (int r = 0; r < 16; ++r) {
        const float pv = exp2f(s0[r] + mv[r >> 2][r & 3]);
        s0[r] = pv;
        lpart += pv;
      }
    }
    {
      const f32x4* mv = (const f32x4*)(mperm + (t & 1) * 64 + 32 + hi * 16);
#pragma unroll
      for (int r = 0; r < 16; ++r) {
        const float pv = exp2f(s1[r] + mv[r >> 2][r & 3]);
        s1[r] = pv;
        lpart += pv;
      }
    }

    // ---- PV: assemble P^T B-frags (cvt_pk + shfl), accumulate ctx^T ----
    __builtin_amdgcn_s_setprio(1);
#pragma unroll
    for (int ks = 0; ks < 4; ++ks) {
      const f32x16& S = (ks < 2) ? s0 : s1;
      const int r0 = (ks & 1) * 8;
      const unsigned d0 = cvt_pk(S[r0 + 0], S[r0 + 1]);
      const unsigned d1 = cvt_pk(S[r0 + 2], S[r0 + 3]);
      const unsigned d2 = cvt_pk(S[r0 + 4], S[r0 + 5]);
      const unsigned d3 = cvt_pk(S[r0 + 6], S[r0 + 7]);
      const unsigned x0 = __shfl_xor(d0, 32);
      const unsigned x1 = __shfl_xor(d1, 32);
      const unsigned x2 = __shfl_xor(d2, 32);
      const unsigned x3 = __shfl_xor(d3, 32);
      union { unsigned u[4]; short8 v; } pf;
      pf.u[0] = hi ? x2 : d0;
      pf.u[1] = hi ? x3 : d1;
      pf.u[2] = hi ? d2 : x0;
      pf.u[3] = hi ? d3 : x1;
      const int off = (((ks << 5) | (hi << 4)) ^ swz);
      const short8 vf0 = *(const short8*)(VsB + bufo + (l31 << 7) + off);
      c0 = __builtin_amdgcn_mfma_f32_32x32x16_bf16(vf0, pf.v, c0, 0, 0, 0);
      const short8 vf1 = *(const short8*)(VsB + bufo + ((32 + l31) << 7) + off);
      c1 = __builtin_amdgcn_mfma_f32_32x32x16_bf16(vf1, pf.v, c1, 0, 0, 0);
    }
    __builtin_amdgcn_s_setprio(0);
  }

  const float ltot = lpart + __shfl_xor(lpart, 32);
  const float inv = 1.f / ltot;

  // ---- epilogue: cvt_pk pairs -> b64 LDS writes -> coalesced stores ----
  __syncthreads();
  __hip_bfloat16* cb = (__hip_bfloat16*)(smem + w * 4608);  // [32][72]
#pragma unroll
  for (int mg = 0; mg < 2; ++mg) {
    const f32x16& cc = mg ? c1 : c0;
#pragma unroll
    for (int rr = 0; rr < 4; ++rr) {
      const unsigned u0 = cvt_pk(cc[rr * 4 + 0] * inv, cc[rr * 4 + 1] * inv);
      const unsigned u1 = cvt_pk(cc[rr * 4 + 2] * inv, cc[rr * 4 + 3] * inv);
      *(uint2*)(cb + l31 * 72 + mg * 32 + 4 * hi + 8 * rr) = uint2{u0, u1};
    }
  }
  __syncthreads();
  const __hip_bfloat16* crd =
      (const __hip_bfloat16*)(smem + w * 4608) + (l >> 1) * 72 + (l & 1) * 8;
  __hip_bfloat16* gout =
      ctx + ((size_t)b * NS + q0 + (l >> 1)) * ND + h * NDH + (l & 1) * 8;
#pragma unroll
  for (int i = 0; i < 4; ++i)
    *(short8*)(gout + i * 16) = *(const short8*)(crd + i * 16);
#undef STAGE
}

// ---------------- MFMA GEMM (output proj): f32 out ------------------------
__global__ __launch_bounds__(256) void gemm_bt_mfma_kernel(
    const __hip_bfloat16* __restrict__ A, const __hip_bfloat16* __restrict__ Bt,
    const float* __restrict__ bias, float* __restrict__ Cout,
    int M, int N, int K) {
  __shared__ __hip_bfloat16 As[128 * 32];
  __shared__ __hip_bfloat16 Bs[64 * 32];
  const int tid = threadIdx.x;
  const int w = tid >> 6, l = tid & 63;
  const int lk = l & 15, lt = l >> 4;
  const int m0 = blockIdx.y * 128, n0 = blockIdx.x * 64;
  const int wr = w >> 1, wc = w & 1;

  f32x4 acc[4][2] = {};

  const int arow = w * 32 + (l >> 2);
  const int acol = (l & 3) * 8;
  const __hip_bfloat16* aptr = A + (size_t)(m0 + arow) * K + acol;
  const int brow = w * 16 + (l >> 2);
  const __hip_bfloat16* bptr = Bt + (size_t)(n0 + brow) * K + acol;
  __hip_bfloat16* asb = As + w * 1024;
  __hip_bfloat16* bsb = Bs + w * 512;

  for (int k0 = 0; k0 < K; k0 += 32) {
    __syncthreads();
    async_ld16(aptr + k0, asb);
    async_ld16(aptr + (size_t)16 * K + k0, asb + 512);
    async_ld16(bptr + k0, bsb);
    __syncthreads();

    short8 af[4], bf[2];
#pragma unroll
    for (int m = 0; m < 4; ++m)
      af[m] = *(const short8*)(As + (wr * 64 + m * 16 + lk) * 32 + lt * 8);
#pragma unroll
    for (int n = 0; n < 2; ++n)
      bf[n] = *(const short8*)(Bs + (wc * 32 + n * 16 + lk) * 32 + lt * 8);
#pragma unroll
    for (int m = 0; m < 4; ++m)
#pragma unroll
      for (int n = 0; n < 2; ++n)
        acc[m][n] =
            __builtin_amdgcn_mfma_f32_16x16x32_bf16(af[m], bf[n], acc[m][n], 0, 0, 0);
  }

#pragma unroll
  for (int n = 0; n < 2; ++n) {
    const int col = n0 + wc * 32 + n * 16 + lk;
    const float bb = bias[col];
#pragma unroll
    for (int m = 0; m < 4; ++m) {
      const int row = m0 + wr * 64 + m * 16 + lt * 4;
#pragma unroll
      for (int r = 0; r < 4; ++r)
        Cout[(size_t)(row + r) * N + col] = acc[m][n][r] + bb;
    }
  }
}

extern "C" void kernel_launch(void* const* d_in, const int* in_sizes, int n_in,
                              void* d_out, int out_size, void* d_ws, size_t ws_size,
                              hipStream_t stream) {
  const float* x    = (const float*)d_in[0];
  const float* mask = (const float*)d_in[1];
  const float* wq   = (const float*)d_in[2];
  const float* bq   = (const float*)d_in[3];
  const float* wk   = (const float*)d_in[4];
  const float* bk   = (const float*)d_in[5];
  const float* wv   = (const float*)d_in[6];
  const float* bv   = (const float*)d_in[7];
  const float* wo   = (const float*)d_in[8];
  const float* bo   = (const float*)d_in[9];
  float* out = (float*)d_out;

  const size_t mat = (size_t)NM * ND;
  const size_t wmat = (size_t)ND * ND;
  __hip_bfloat16* xb    = (__hip_bfloat16*)d_ws;
  __hip_bfloat16* WtAll = xb + mat;
  __hip_bfloat16* Qw    = WtAll + 4 * wmat;
  __hip_bfloat16* Kw    = Qw + mat;
  __hip_bfloat16* Vtw   = Kw + mat;
  __hip_bfloat16* Cw    = Vtw + mat;

  convert_bf16_kernel<<<(NM * ND / 8 + 255) / 256, 256, 0, stream>>>(
      x, xb, NM * ND / 8);
  transpose_w_kernel<<<dim3(ND / 64, ND / 64, 4), 256, 0, stream>>>(
      wq, wk, wv, wo, WtAll);

  qkv_gemm_kernel<<<dim3(3 * ND / 64, NM / 128), 256, 0, stream>>>(
      xb, WtAll, bq, bk, bv, Qw, Kw, Vtw);

  mha_mfma32_kernel<<<dim3(NS / 128, NH, NB), 256, 0, stream>>>(
      Qw, Kw, Vtw, mask, Cw);

  gemm_bt_mfma_kernel<<<dim3(ND / 64, NM / 128), 256, 0, stream>>>(
      Cw, WtAll + 3 * wmat, bo, out, NM, ND, ND);
}

// Round 6
// 220.734 us; speedup vs baseline: 1.0245x; 1.0245x over previous
//
#include <hip/hip_runtime.h>
#include <hip/hip_bf16.h>

#define NB 4
#define NS 2048
#define ND 768
#define NH 12
#define NDH 64
#define NM (NB * NS)  // 8192

// fold 1/sqrt(64) * log2(e) into Q so softmax = exp2(s + m)
#define QSCALE 0.1803368867f
#define MSCALE (-1.442695041e9f)

typedef __attribute__((ext_vector_type(8))) short short8;    // 8 x bf16
typedef __attribute__((ext_vector_type(4))) float f32x4;
typedef __attribute__((ext_vector_type(16))) float f32x16;

__device__ __forceinline__ void async_ld16(const void* g, void* l) {
  __builtin_amdgcn_global_load_lds(
      (const __attribute__((address_space(1))) void*)g,
      (__attribute__((address_space(3))) void*)l, 16, 0, 0);
}

// plain scalar packing — compiler pairs these into v_cvt_pk_bf16_f32 (m240)
__device__ __forceinline__ unsigned pack_bf16(float a, float b) {
  return ((unsigned)__bfloat16_as_ushort(__float2bfloat16(b)) << 16) |
         (unsigned)__bfloat16_as_ushort(__float2bfloat16(a));
}

// ---------------- f32 -> bf16 convert (vectorized, 8/thread) --------------
__global__ __launch_bounds__(256) void convert_bf16_kernel(
    const float* __restrict__ in, __hip_bfloat16* __restrict__ out, int n8) {
  const int i = blockIdx.x * 256 + threadIdx.x;
  if (i >= n8) return;
  const float4 a = ((const float4*)in)[i * 2];
  const float4 b = ((const float4*)in)[i * 2 + 1];
  short8 v;
  __hip_bfloat16* p = (__hip_bfloat16*)&v;
  p[0] = __float2bfloat16(a.x); p[1] = __float2bfloat16(a.y);
  p[2] = __float2bfloat16(a.z); p[3] = __float2bfloat16(a.w);
  p[4] = __float2bfloat16(b.x); p[5] = __float2bfloat16(b.y);
  p[6] = __float2bfloat16(b.z); p[7] = __float2bfloat16(b.w);
  ((short8*)out)[i] = v;
}

// ------- weight transpose+convert: W[K][N] f32 -> Wt[N][K] bf16 -----------
__global__ __launch_bounds__(256) void transpose_w_kernel(
    const float* __restrict__ w0, const float* __restrict__ w1,
    const float* __restrict__ w2, const float* __restrict__ w3,
    __hip_bfloat16* __restrict__ WtAll) {
  __shared__ __hip_bfloat16 tile[64][66];
  const float* src = blockIdx.z == 0 ? w0 : blockIdx.z == 1 ? w1
                   : blockIdx.z == 2 ? w2 : w3;
  __hip_bfloat16* dst = WtAll + (size_t)blockIdx.z * ND * ND;
  const int kk0 = blockIdx.y * 64, nn0 = blockIdx.x * 64;
  const int t = threadIdx.x;
#pragma unroll
  for (int p = 0; p < 4; ++p) {
    const int idx = p * 256 + t;
    const int k = idx >> 4;
    const int c = (idx & 15) * 4;
    const float4 v = *(const float4*)(src + (size_t)(kk0 + k) * ND + nn0 + c);
    __hip_bfloat162* tp = (__hip_bfloat162*)&tile[k][c];
    tp[0] = __hip_bfloat162{__float2bfloat16(v.x), __float2bfloat16(v.y)};
    tp[1] = __hip_bfloat162{__float2bfloat16(v.z), __float2bfloat16(v.w)};
  }
  __syncthreads();
#pragma unroll
  for (int p = 0; p < 2; ++p) {
    const int idx = p * 256 + t;
    const int n = idx >> 3;
    const int kb = (idx & 7) * 8;
    short8 v;
    __hip_bfloat16* pv = (__hip_bfloat16*)&v;
#pragma unroll
    for (int j = 0; j < 8; ++j) pv[j] = tile[kb + j][n];
    *(short8*)(dst + (size_t)(nn0 + n) * ND + kk0 + kb) = v;
  }
}

// ------- fused QKV GEMM: [M,768] @ Wt[2304,768]^T -> Q,K rowmajor + V^T ---
// Q output is pre-scaled by QSCALE (softmax exp2 domain).
__global__ __launch_bounds__(256) void qkv_gemm_kernel(
    const __hip_bfloat16* __restrict__ A,
    const __hip_bfloat16* __restrict__ Bt,
    const float* __restrict__ bq, const float* __restrict__ bk,
    const float* __restrict__ bv,
    __hip_bfloat16* __restrict__ Qw, __hip_bfloat16* __restrict__ Kw,
    __hip_bfloat16* __restrict__ Vt) {
  __shared__ __hip_bfloat16 As[128 * 32];
  __shared__ __hip_bfloat16 Bs[64 * 32];
  const int K = ND;
  const int tid = threadIdx.x;
  const int w = tid >> 6, l = tid & 63;
  const int lk = l & 15, lt = l >> 4;
  const int m0 = blockIdx.y * 128, n0 = blockIdx.x * 64;
  const int wr = w >> 1, wc = w & 1;

  f32x4 acc[4][2] = {};

  const int arow = w * 32 + (l >> 2);
  const int acol = (l & 3) * 8;
  const __hip_bfloat16* aptr = A + (size_t)(m0 + arow) * K + acol;
  const int brow = w * 16 + (l >> 2);
  const __hip_bfloat16* bptr = Bt + (size_t)(n0 + brow) * K + acol;
  __hip_bfloat16* asb = As + w * 1024;
  __hip_bfloat16* bsb = Bs + w * 512;

  for (int k0 = 0; k0 < K; k0 += 32) {
    __syncthreads();
    async_ld16(aptr + k0, asb);
    async_ld16(aptr + (size_t)16 * K + k0, asb + 512);
    async_ld16(bptr + k0, bsb);
    __syncthreads();

    short8 af[4], bf[2];
#pragma unroll
    for (int m = 0; m < 4; ++m)
      af[m] = *(const short8*)(As + (wr * 64 + m * 16 + lk) * 32 + lt * 8);
#pragma unroll
    for (int n = 0; n < 2; ++n)
      bf[n] = *(const short8*)(Bs + (wc * 32 + n * 16 + lk) * 32 + lt * 8);
#pragma unroll
    for (int m = 0; m < 4; ++m)
#pragma unroll
      for (int n = 0; n < 2; ++n)
        acc[m][n] =
            __builtin_amdgcn_mfma_f32_16x16x32_bf16(af[m], bf[n], acc[m][n], 0, 0, 0);
  }

  const int mi = n0 / ND;          // 0=Q, 1=K, 2=V
  const int nbase = n0 - mi * ND;
  const float* bp = mi == 0 ? bq : mi == 1 ? bk : bv;
  const float oscale = (mi == 0) ? QSCALE : 1.f;

#pragma unroll
  for (int n = 0; n < 2; ++n) {
    const int col = nbase + wc * 32 + n * 16 + lk;
    const float bb = bp[col];
#pragma unroll
    for (int m = 0; m < 4; ++m) {
      const int row = m0 + wr * 64 + m * 16 + lt * 4;
#pragma unroll
      for (int r = 0; r < 4; ++r) {
        const float v = (acc[m][n][r] + bb) * oscale;
        if (mi < 2) {
          (mi ? Kw : Qw)[(size_t)(row + r) * ND + col] = __float2bfloat16(v);
        } else {
          const int mrow = row + r;
          const int bidx = mrow >> 11, s = mrow & 2047;
          const int hh = col >> 6, dh = col & 63;
          Vt[(((size_t)bidx * NH + hh) * NDH + dh) * NS + s] = __float2bfloat16(v);
        }
      }
    }
  }
}

// ---------------- MFMA-32x32 flash attention, register-resident P ---------
// QK^T swapped (D = K.Q^T): lane owns q = lane&31, key = crow(r,hi).
// Mask (pre-scaled by -1e9*log2e) is loaded INTO the MFMA accumulator init,
// so softmax is exactly p = exp2(s): 2 VALU ops per logit.
__global__ __launch_bounds__(256) void mha_mfma32_kernel(
    const __hip_bfloat16* __restrict__ Qb, const __hip_bfloat16* __restrict__ Kb,
    const __hip_bfloat16* __restrict__ Vt, const float* __restrict__ mask,
    __hip_bfloat16* __restrict__ ctx) {
  __shared__ __align__(16) char smem[33280];
  char* KsB = smem;
  char* VsB = smem + 16384;
  float* mperm = (float*)(smem + 32768);

  const int b = blockIdx.z, h = blockIdx.y;
  const int tid = threadIdx.x;
  const int w = tid >> 6, l = tid & 63;
  const int l31 = l & 31, hi = l >> 5;
  const int q0 = blockIdx.x * 128 + w * 32;

  const __hip_bfloat16* qp = Qb + ((size_t)b * NS + q0 + l31) * ND + h * NDH;
  short8 qf[4];
#pragma unroll
  for (int ks = 0; ks < 4; ++ks)
    qf[ks] = *(const short8*)(qp + ks * 16 + hi * 8);

  f32x16 c0 = {}, c1 = {};
  float lpart = 0.f;

  const int srow = l >> 3, slot = l & 7;
  const int key1 = w * 8 + srow, key2 = key1 + 32;
  const __hip_bfloat16* kg1 =
      Kb + ((size_t)b * NS + key1) * ND + h * NDH + (slot ^ (key1 & 7)) * 8;
  const __hip_bfloat16* kg2 =
      Kb + ((size_t)b * NS + key2) * ND + h * NDH + (slot ^ (key2 & 7)) * 8;
  const __hip_bfloat16* vg1 =
      Vt + (((size_t)b * NH + h) * NDH + key1) * NS + (slot ^ (key1 & 7)) * 8;
  const __hip_bfloat16* vg2 =
      Vt + (((size_t)b * NH + h) * NDH + key2) * NS + (slot ^ (key2 & 7)) * 8;
  const int ldsoff = w * 1024;
  const float* mb = mask + (size_t)b * NS;

  // mask crow-permutation: slot i = g*32 + hi*16 + r  <->  key g*32+crow(r,hi)
  const int mg_ = tid >> 5, mhi_ = (tid >> 4) & 1, mr_ = tid & 15;
  const int mkey = mg_ * 32 + 4 * mhi_ + (mr_ & 3) + 8 * (mr_ >> 2);

#define STAGE(buf, t)                                                        \
  {                                                                          \
    const size_t koff = (size_t)(t) * 64 * ND;                               \
    char* kd = KsB + (buf) * 8192 + ldsoff;                                  \
    char* vd = VsB + (buf) * 8192 + ldsoff;                                  \
    async_ld16(kg1 + koff, kd);                                              \
    async_ld16(kg2 + koff, kd + 4096);                                       \
    async_ld16(vg1 + (t) * 64, vd);                                          \
    async_ld16(vg2 + (t) * 64, vd + 4096);                                   \
    if (tid < 64) mperm[(buf) * 64 + tid] = mb[(t) * 64 + mkey] * MSCALE;    \
  }

  STAGE(0, 0);
  const int swz = (l31 & 7) << 4;

  for (int t = 0; t < 32; ++t) {
    __syncthreads();  // stage(t) complete; buf((t+1)&1) free
    if (t + 1 < 32) STAGE((t + 1) & 1, t + 1);
    const int bufo = (t & 1) * 8192;

    // ---- QK^T, accumulator pre-loaded with mask bias ----
    f32x16 s0, s1;
    {
      const f32x4* mva = (const f32x4*)(mperm + (t & 1) * 64 + hi * 16);
      const f32x4* mvb = (const f32x4*)(mperm + (t & 1) * 64 + 32 + hi * 16);
#pragma unroll
      for (int r = 0; r < 16; ++r) {
        s0[r] = mva[r >> 2][r & 3];
        s1[r] = mvb[r >> 2][r & 3];
      }
    }
#pragma unroll
    for (int ks = 0; ks < 4; ++ks) {
      const int off = (((ks << 5) | (hi << 4)) ^ swz);
      const short8 kf0 = *(const short8*)(KsB + bufo + (l31 << 7) + off);
      s0 = __builtin_amdgcn_mfma_f32_32x32x16_bf16(kf0, qf[ks], s0, 0, 0, 0);
      const short8 kf1 = *(const short8*)(KsB + bufo + ((32 + l31) << 7) + off);
      s1 = __builtin_amdgcn_mfma_f32_32x32x16_bf16(kf1, qf[ks], s1, 0, 0, 0);
    }

    // ---- softmax: p = exp2(s), native v_exp_f32 ----
#pragma unroll
    for (int r = 0; r < 16; ++r) {
      const float pv = exp2f(s0[r]);
      s0[r] = pv;
      lpart += pv;
    }
#pragma unroll
    for (int r = 0; r < 16; ++r) {
      const float pv = exp2f(s1[r]);
      s1[r] = pv;
      lpart += pv;
    }

    // ---- PV: assemble P^T B-frags; 2 shfl + 6 selects per ks ----
#pragma unroll
    for (int ks = 0; ks < 4; ++ks) {
      const f32x16& S = (ks < 2) ? s0 : s1;
      const int r0 = (ks & 1) * 8;
      const unsigned d0 = pack_bf16(S[r0 + 0], S[r0 + 1]);
      const unsigned d1 = pack_bf16(S[r0 + 2], S[r0 + 3]);
      const unsigned d2 = pack_bf16(S[r0 + 4], S[r0 + 5]);
      const unsigned d3 = pack_bf16(S[r0 + 6], S[r0 + 7]);
      // send the words the partner half needs; receive ours
      const unsigned y0 = hi ? d0 : d2;
      const unsigned y1 = hi ? d1 : d3;
      const unsigned z0 = __shfl_xor(y0, 32);
      const unsigned z1 = __shfl_xor(y1, 32);
      union { unsigned u[4]; short8 v; } pf;
      pf.u[0] = hi ? z0 : d0;
      pf.u[1] = hi ? z1 : d1;
      pf.u[2] = hi ? d2 : z0;
      pf.u[3] = hi ? d3 : z1;
      const int off = (((ks << 5) | (hi << 4)) ^ swz);
      const short8 vf0 = *(const short8*)(VsB + bufo + (l31 << 7) + off);
      c0 = __builtin_amdgcn_mfma_f32_32x32x16_bf16(vf0, pf.v, c0, 0, 0, 0);
      const short8 vf1 = *(const short8*)(VsB + bufo + ((32 + l31) << 7) + off);
      c1 = __builtin_amdgcn_mfma_f32_32x32x16_bf16(vf1, pf.v, c1, 0, 0, 0);
    }
  }

  const float ltot = lpart + __shfl_xor(lpart, 32);
  const float inv = 1.f / ltot;

  // ---- epilogue: LDS bounce -> coalesced bf16 stores ----
  __syncthreads();
  __hip_bfloat16* cb = (__hip_bfloat16*)(smem + w * 4608);  // [32][72]
#pragma unroll
  for (int mg = 0; mg < 2; ++mg) {
    const f32x16& cc = mg ? c1 : c0;
#pragma unroll
    for (int rr = 0; rr < 4; ++rr) {
      const unsigned u0 = pack_bf16(cc[rr * 4 + 0] * inv, cc[rr * 4 + 1] * inv);
      const unsigned u1 = pack_bf16(cc[rr * 4 + 2] * inv, cc[rr * 4 + 3] * inv);
      *(uint2*)(cb + l31 * 72 + mg * 32 + 4 * hi + 8 * rr) = uint2{u0, u1};
    }
  }
  __syncthreads();
  const __hip_bfloat16* crd =
      (const __hip_bfloat16*)(smem + w * 4608) + (l >> 1) * 72 + (l & 1) * 8;
  __hip_bfloat16* gout =
      ctx + ((size_t)b * NS + q0 + (l >> 1)) * ND + h * NDH + (l & 1) * 8;
#pragma unroll
  for (int i = 0; i < 4; ++i)
    *(short8*)(gout + i * 16) = *(const short8*)(crd + i * 16);
#undef STAGE
}

// ---------------- MFMA GEMM (output proj): f32 out ------------------------
__global__ __launch_bounds__(256) void gemm_bt_mfma_kernel(
    const __hip_bfloat16* __restrict__ A, const __hip_bfloat16* __restrict__ Bt,
    const float* __restrict__ bias, float* __restrict__ Cout,
    int M, int N, int K) {
  __shared__ __hip_bfloat16 As[128 * 32];
  __shared__ __hip_bfloat16 Bs[64 * 32];
  const int tid = threadIdx.x;
  const int w = tid >> 6, l = tid & 63;
  const int lk = l & 15, lt = l >> 4;
  const int m0 = blockIdx.y * 128, n0 = blockIdx.x * 64;
  const int wr = w >> 1, wc = w & 1;

  f32x4 acc[4][2] = {};

  const int arow = w * 32 + (l >> 2);
  const int acol = (l & 3) * 8;
  const __hip_bfloat16* aptr = A + (size_t)(m0 + arow) * K + acol;
  const int brow = w * 16 + (l >> 2);
  const __hip_bfloat16* bptr = Bt + (size_t)(n0 + brow) * K + acol;
  __hip_bfloat16* asb = As + w * 1024;
  __hip_bfloat16* bsb = Bs + w * 512;

  for (int k0 = 0; k0 < K; k0 += 32) {
    __syncthreads();
    async_ld16(aptr + k0, asb);
    async_ld16(aptr + (size_t)16 * K + k0, asb + 512);
    async_ld16(bptr + k0, bsb);
    __syncthreads();

    short8 af[4], bf[2];
#pragma unroll
    for (int m = 0; m < 4; ++m)
      af[m] = *(const short8*)(As + (wr * 64 + m * 16 + lk) * 32 + lt * 8);
#pragma unroll
    for (int n = 0; n < 2; ++n)
      bf[n] = *(const short8*)(Bs + (wc * 32 + n * 16 + lk) * 32 + lt * 8);
#pragma unroll
    for (int m = 0; m < 4; ++m)
#pragma unroll
      for (int n = 0; n < 2; ++n)
        acc[m][n] =
            __builtin_amdgcn_mfma_f32_16x16x32_bf16(af[m], bf[n], acc[m][n], 0, 0, 0);
  }

#pragma unroll
  for (int n = 0; n < 2; ++n) {
    const int col = n0 + wc * 32 + n * 16 + lk;
    const float bb = bias[col];
#pragma unroll
    for (int m = 0; m < 4; ++m) {
      const int row = m0 + wr * 64 + m * 16 + lt * 4;
#pragma unroll
      for (int r = 0; r < 4; ++r)
        Cout[(size_t)(row + r) * N + col] = acc[m][n][r] + bb;
    }
  }
}

extern "C" void kernel_launch(void* const* d_in, const int* in_sizes, int n_in,
                              void* d_out, int out_size, void* d_ws, size_t ws_size,
                              hipStream_t stream) {
  const float* x    = (const float*)d_in[0];
  const float* mask = (const float*)d_in[1];
  const float* wq   = (const float*)d_in[2];
  const float* bq   = (const float*)d_in[3];
  const float* wk   = (const float*)d_in[4];
  const float* bk   = (const float*)d_in[5];
  const float* wv   = (const float*)d_in[6];
  const float* bv   = (const float*)d_in[7];
  const float* wo   = (const float*)d_in[8];
  const float* bo   = (const float*)d_in[9];
  float* out = (float*)d_out;

  const size_t mat = (size_t)NM * ND;
  const size_t wmat = (size_t)ND * ND;
  __hip_bfloat16* xb    = (__hip_bfloat16*)d_ws;
  __hip_bfloat16* WtAll = xb + mat;
  __hip_bfloat16* Qw    = WtAll + 4 * wmat;
  __hip_bfloat16* Kw    = Qw + mat;
  __hip_bfloat16* Vtw   = Kw + mat;
  __hip_bfloat16* Cw    = Vtw + mat;

  convert_bf16_kernel<<<(NM * ND / 8 + 255) / 256, 256, 0, stream>>>(
      x, xb, NM * ND / 8);
  transpose_w_kernel<<<dim3(ND / 64, ND / 64, 4), 256, 0, stream>>>(
      wq, wk, wv, wo, WtAll);

  qkv_gemm_kernel<<<dim3(3 * ND / 64, NM / 128), 256, 0, stream>>>(
      xb, WtAll, bq, bk, bv, Qw, Kw, Vtw);

  mha_mfma32_kernel<<<dim3(NS / 128, NH, NB), 256, 0, stream>>>(
      Qw, Kw, Vtw, mask, Cw);

  gemm_bt_mfma_kernel<<<dim3(ND / 64, NM / 128), 256, 0, stream>>>(
      Cw, WtAll + 3 * wmat, bo, out, NM, ND, ND);
}

// Round 7
// 219.111 us; speedup vs baseline: 1.0321x; 1.0074x over previous
//
#include <hip/hip_runtime.h>
#include <hip/hip_bf16.h>

#define NB 4
#define NS 2048
#define ND 768
#define NH 12
#define NDH 64
#define NM (NB * NS)  // 8192

// fold 1/sqrt(64) * log2(e) into Q so softmax = exp2(s + m)
#define QSCALE 0.1803368867f
#define MSCALE (-1.442695041e9f)

typedef __attribute__((ext_vector_type(8))) short short8;    // 8 x bf16
typedef __attribute__((ext_vector_type(4))) float f32x4;
typedef __attribute__((ext_vector_type(16))) float f32x16;

__device__ __forceinline__ void async_ld16(const void* g, void* l) {
  __builtin_amdgcn_global_load_lds(
      (const __attribute__((address_space(1))) void*)g,
      (__attribute__((address_space(3))) void*)l, 16, 0, 0);
}

// plain scalar packing — compiler pairs these into v_cvt_pk_bf16_f32
__device__ __forceinline__ unsigned pack_bf16(float a, float b) {
  return ((unsigned)__bfloat16_as_ushort(__float2bfloat16(b)) << 16) |
         (unsigned)__bfloat16_as_ushort(__float2bfloat16(a));
}

// ---------------- f32 -> bf16 convert (vectorized, 8/thread) --------------
__global__ __launch_bounds__(256) void convert_bf16_kernel(
    const float* __restrict__ in, __hip_bfloat16* __restrict__ out, int n8) {
  const int i = blockIdx.x * 256 + threadIdx.x;
  if (i >= n8) return;
  const float4 a = ((const float4*)in)[i * 2];
  const float4 b = ((const float4*)in)[i * 2 + 1];
  short8 v;
  __hip_bfloat16* p = (__hip_bfloat16*)&v;
  p[0] = __float2bfloat16(a.x); p[1] = __float2bfloat16(a.y);
  p[2] = __float2bfloat16(a.z); p[3] = __float2bfloat16(a.w);
  p[4] = __float2bfloat16(b.x); p[5] = __float2bfloat16(b.y);
  p[6] = __float2bfloat16(b.z); p[7] = __float2bfloat16(b.w);
  ((short8*)out)[i] = v;
}

// ------- mask precompute: crow-permuted, scaled by -1e9*log2e -------------
// slot layout per 64-key tile: slot = g*32 + hi*16 + r <-> key = g*32 + crow
__global__ __launch_bounds__(256) void mask_perm_kernel(
    const float* __restrict__ mask, float* __restrict__ mperm_g) {
  const int idx = blockIdx.x * 256 + threadIdx.x;  // 0..8191
  const int b = idx >> 11;
  const int sb = idx & 2047;
  const int tile = sb >> 6, slot = sb & 63;
  const int g = slot >> 5, hh = (slot >> 4) & 1, r = slot & 15;
  const int key = tile * 64 + g * 32 + 4 * hh + (r & 3) + 8 * (r >> 2);
  mperm_g[idx] = mask[b * NS + key] * MSCALE;
}

// ------- weight transpose+convert: W[K][N] f32 -> Wt[N][K] bf16 -----------
__global__ __launch_bounds__(256) void transpose_w_kernel(
    const float* __restrict__ w0, const float* __restrict__ w1,
    const float* __restrict__ w2, const float* __restrict__ w3,
    __hip_bfloat16* __restrict__ WtAll) {
  __shared__ __hip_bfloat16 tile[64][66];
  const float* src = blockIdx.z == 0 ? w0 : blockIdx.z == 1 ? w1
                   : blockIdx.z == 2 ? w2 : w3;
  __hip_bfloat16* dst = WtAll + (size_t)blockIdx.z * ND * ND;
  const int kk0 = blockIdx.y * 64, nn0 = blockIdx.x * 64;
  const int t = threadIdx.x;
#pragma unroll
  for (int p = 0; p < 4; ++p) {
    const int idx = p * 256 + t;
    const int k = idx >> 4;
    const int c = (idx & 15) * 4;
    const float4 v = *(const float4*)(src + (size_t)(kk0 + k) * ND + nn0 + c);
    __hip_bfloat162* tp = (__hip_bfloat162*)&tile[k][c];
    tp[0] = __hip_bfloat162{__float2bfloat16(v.x), __float2bfloat16(v.y)};
    tp[1] = __hip_bfloat162{__float2bfloat16(v.z), __float2bfloat16(v.w)};
  }
  __syncthreads();
#pragma unroll
  for (int p = 0; p < 2; ++p) {
    const int idx = p * 256 + t;
    const int n = idx >> 3;
    const int kb = (idx & 7) * 8;
    short8 v;
    __hip_bfloat16* pv = (__hip_bfloat16*)&v;
#pragma unroll
    for (int j = 0; j < 8; ++j) pv[j] = tile[kb + j][n];
    *(short8*)(dst + (size_t)(nn0 + n) * ND + kk0 + kb) = v;
  }
}

// ------- fused QKV GEMM: [M,768] @ Wt[2304,768]^T -> Q,K rowmajor + V^T ---
__global__ __launch_bounds__(256) void qkv_gemm_kernel(
    const __hip_bfloat16* __restrict__ A,
    const __hip_bfloat16* __restrict__ Bt,
    const float* __restrict__ bq, const float* __restrict__ bk,
    const float* __restrict__ bv,
    __hip_bfloat16* __restrict__ Qw, __hip_bfloat16* __restrict__ Kw,
    __hip_bfloat16* __restrict__ Vt) {
  __shared__ __hip_bfloat16 As[128 * 32];
  __shared__ __hip_bfloat16 Bs[64 * 32];
  const int K = ND;
  const int tid = threadIdx.x;
  const int w = tid >> 6, l = tid & 63;
  const int lk = l & 15, lt = l >> 4;
  const int m0 = blockIdx.y * 128, n0 = blockIdx.x * 64;
  const int wr = w >> 1, wc = w & 1;

  f32x4 acc[4][2] = {};

  const int arow = w * 32 + (l >> 2);
  const int acol = (l & 3) * 8;
  const __hip_bfloat16* aptr = A + (size_t)(m0 + arow) * K + acol;
  const int brow = w * 16 + (l >> 2);
  const __hip_bfloat16* bptr = Bt + (size_t)(n0 + brow) * K + acol;
  __hip_bfloat16* asb = As + w * 1024;
  __hip_bfloat16* bsb = Bs + w * 512;

  for (int k0 = 0; k0 < K; k0 += 32) {
    __syncthreads();
    async_ld16(aptr + k0, asb);
    async_ld16(aptr + (size_t)16 * K + k0, asb + 512);
    async_ld16(bptr + k0, bsb);
    __syncthreads();

    short8 af[4], bf[2];
#pragma unroll
    for (int m = 0; m < 4; ++m)
      af[m] = *(const short8*)(As + (wr * 64 + m * 16 + lk) * 32 + lt * 8);
#pragma unroll
    for (int n = 0; n < 2; ++n)
      bf[n] = *(const short8*)(Bs + (wc * 32 + n * 16 + lk) * 32 + lt * 8);
#pragma unroll
    for (int m = 0; m < 4; ++m)
#pragma unroll
      for (int n = 0; n < 2; ++n)
        acc[m][n] =
            __builtin_amdgcn_mfma_f32_16x16x32_bf16(af[m], bf[n], acc[m][n], 0, 0, 0);
  }

  const int mi = n0 / ND;          // 0=Q, 1=K, 2=V
  const int nbase = n0 - mi * ND;
  const float* bp = mi == 0 ? bq : mi == 1 ? bk : bv;
  const float oscale = (mi == 0) ? QSCALE : 1.f;

#pragma unroll
  for (int n = 0; n < 2; ++n) {
    const int col = nbase + wc * 32 + n * 16 + lk;
    const float bb = bp[col];
#pragma unroll
    for (int m = 0; m < 4; ++m) {
      const int row = m0 + wr * 64 + m * 16 + lt * 4;
#pragma unroll
      for (int r = 0; r < 4; ++r) {
        const float v = (acc[m][n][r] + bb) * oscale;
        if (mi < 2) {
          (mi ? Kw : Qw)[(size_t)(row + r) * ND + col] = __float2bfloat16(v);
        } else {
          const int mrow = row + r;
          const int bidx = mrow >> 11, s = mrow & 2047;
          const int hh = col >> 6, dh = col & 63;
          Vt[(((size_t)bidx * NH + hh) * NDH + dh) * NS + s] = __float2bfloat16(v);
        }
      }
    }
  }
}

// ---------------- MFMA-32x32 flash attention, register-resident P ---------
// Triple-buffered K/V staging, prefetch depth 2, counted vmcnt across raw
// s_barrier (T3/T4): loads for tiles t+1,t+2 stay in flight during tile t.
__global__ __launch_bounds__(256) void mha_mfma32_kernel(
    const __hip_bfloat16* __restrict__ Qb, const __hip_bfloat16* __restrict__ Kb,
    const __hip_bfloat16* __restrict__ Vt, const float* __restrict__ mperm_g,
    __hip_bfloat16* __restrict__ ctx) {
  // [0,24576): K bufs (3x8KB) | [24576,49152): V bufs | [49152,+768): mask
  __shared__ __align__(16) char smem[49920];
  char* KsB = smem;
  char* VsB = smem + 24576;
  char* mpermB = smem + 49152;
  const float* mpermF = (const float*)mpermB;

  const int b = blockIdx.z, h = blockIdx.y;
  const int tid = threadIdx.x;
  const int w = tid >> 6, l = tid & 63;
  const int l31 = l & 31, hi = l >> 5;
  const int q0 = blockIdx.x * 128 + w * 32;

  const __hip_bfloat16* qp = Qb + ((size_t)b * NS + q0 + l31) * ND + h * NDH;
  short8 qf[4];
#pragma unroll
  for (int ks = 0; ks < 4; ++ks)
    qf[ks] = *(const short8*)(qp + ks * 16 + hi * 8);

  f32x16 c0 = {}, c1 = {};
  float lpart = 0.f;

  const int srow = l >> 3, slot = l & 7;
  const int key1 = w * 8 + srow, key2 = key1 + 32;
  const __hip_bfloat16* kg1 =
      Kb + ((size_t)b * NS + key1) * ND + h * NDH + (slot ^ (key1 & 7)) * 8;
  const __hip_bfloat16* kg2 =
      Kb + ((size_t)b * NS + key2) * ND + h * NDH + (slot ^ (key2 & 7)) * 8;
  const __hip_bfloat16* vg1 =
      Vt + (((size_t)b * NH + h) * NDH + key1) * NS + (slot ^ (key1 & 7)) * 8;
  const __hip_bfloat16* vg2 =
      Vt + (((size_t)b * NH + h) * NDH + key2) * NS + (slot ^ (key2 & 7)) * 8;
  const int ldsoff = w * 1024;
  const float* mg = mperm_g + (size_t)b * NS;  // crow-permuted, pre-scaled

  // uniform 5 async loads per wave per stage (vmcnt accounting)
#define STAGE(buf, t)                                                        \
  {                                                                          \
    const size_t koff = (size_t)(t) * 64 * ND;                               \
    char* kd = KsB + (buf) * 8192 + ldsoff;                                  \
    char* vd = VsB + (buf) * 8192 + ldsoff;                                  \
    async_ld16(kg1 + koff, kd);                                              \
    async_ld16(kg2 + koff, kd + 4096);                                       \
    async_ld16(vg1 + (t) * 64, vd);                                         \
    async_ld16(vg2 + (t) * 64, vd + 4096);                                   \
    if (l < 16) async_ld16(mg + (t) * 64 + l * 4, mpermB + (buf) * 256);     \
  }

  const int swz = (l31 & 7) << 4;

  auto compute_tile = [&](int cur) {
    const int bufo = cur * 8192;
    // ---- QK^T, accumulator pre-loaded with permuted mask bias ----
    f32x16 s0, s1;
    {
      const f32x4* mva = (const f32x4*)(mpermF + cur * 64 + hi * 16);
      const f32x4* mvb = (const f32x4*)(mpermF + cur * 64 + 32 + hi * 16);
#pragma unroll
      for (int r = 0; r < 16; ++r) {
        s0[r] = mva[r >> 2][r & 3];
        s1[r] = mvb[r >> 2][r & 3];
      }
    }
#pragma unroll
    for (int ks = 0; ks < 4; ++ks) {
      const int off = (((ks << 5) | (hi << 4)) ^ swz);
      const short8 kf0 = *(const short8*)(KsB + bufo + (l31 << 7) + off);
      s0 = __builtin_amdgcn_mfma_f32_32x32x16_bf16(kf0, qf[ks], s0, 0, 0, 0);
      const short8 kf1 = *(const short8*)(KsB + bufo + ((32 + l31) << 7) + off);
      s1 = __builtin_amdgcn_mfma_f32_32x32x16_bf16(kf1, qf[ks], s1, 0, 0, 0);
    }

    // ---- softmax: p = exp2(s), native v_exp_f32 ----
#pragma unroll
    for (int r = 0; r < 16; ++r) {
      const float pv = exp2f(s0[r]);
      s0[r] = pv;
      lpart += pv;
    }
#pragma unroll
    for (int r = 0; r < 16; ++r) {
      const float pv = exp2f(s1[r]);
      s1[r] = pv;
      lpart += pv;
    }

    // ---- PV: assemble P^T B-frags; 2 shfl + selects per ks ----
#pragma unroll
    for (int ks = 0; ks < 4; ++ks) {
      const f32x16& S = (ks < 2) ? s0 : s1;
      const int r0 = (ks & 1) * 8;
      const unsigned d0 = pack_bf16(S[r0 + 0], S[r0 + 1]);
      const unsigned d1 = pack_bf16(S[r0 + 2], S[r0 + 3]);
      const unsigned d2 = pack_bf16(S[r0 + 4], S[r0 + 5]);
      const unsigned d3 = pack_bf16(S[r0 + 6], S[r0 + 7]);
      const unsigned y0 = hi ? d0 : d2;
      const unsigned y1 = hi ? d1 : d3;
      const unsigned z0 = __shfl_xor(y0, 32);
      const unsigned z1 = __shfl_xor(y1, 32);
      union { unsigned u[4]; short8 v; } pf;
      pf.u[0] = hi ? z0 : d0;
      pf.u[1] = hi ? z1 : d1;
      pf.u[2] = hi ? d2 : z0;
      pf.u[3] = hi ? d3 : z1;
      const int off = (((ks << 5) | (hi << 4)) ^ swz);
      const short8 vf0 = *(const short8*)(VsB + bufo + (l31 << 7) + off);
      c0 = __builtin_amdgcn_mfma_f32_32x32x16_bf16(vf0, pf.v, c0, 0, 0, 0);
      const short8 vf1 = *(const short8*)(VsB + bufo + ((32 + l31) << 7) + off);
      c1 = __builtin_amdgcn_mfma_f32_32x32x16_bf16(vf1, pf.v, c1, 0, 0, 0);
    }
  };

  STAGE(0, 0);
  STAGE(1, 1);
  int cur = 0;
  for (int t = 0; t < 30; ++t) {
    // wait tile t's 5 loads (tile t+1's 5 stay in flight); retire ds ops
    asm volatile("s_waitcnt vmcnt(5) lgkmcnt(0)" ::: "memory");
    __builtin_amdgcn_s_barrier();
    // all waves finished compute(t-1) -> its buffer is free to restage
    const int nb = (cur + 2 >= 3) ? cur - 1 : cur + 2;
    STAGE(nb, t + 2);
    compute_tile(cur);
    cur = (cur + 1 >= 3) ? 0 : cur + 1;
  }
  // t = 30: tiles 30,31 in flight; wait 30's
  asm volatile("s_waitcnt vmcnt(5) lgkmcnt(0)" ::: "memory");
  __builtin_amdgcn_s_barrier();
  compute_tile(cur);
  cur = (cur + 1 >= 3) ? 0 : cur + 1;
  // t = 31: drain
  asm volatile("s_waitcnt vmcnt(0) lgkmcnt(0)" ::: "memory");
  __builtin_amdgcn_s_barrier();
  compute_tile(cur);

  const float ltot = lpart + __shfl_xor(lpart, 32);
  const float inv = 1.f / ltot;

  // ---- epilogue: LDS bounce -> coalesced bf16 stores ----
  __syncthreads();
  __hip_bfloat16* cb = (__hip_bfloat16*)(smem + w * 4608);  // [32][72]
#pragma unroll
  for (int mg2 = 0; mg2 < 2; ++mg2) {
    const f32x16& cc = mg2 ? c1 : c0;
#pragma unroll
    for (int rr = 0; rr < 4; ++rr) {
      const unsigned u0 = pack_bf16(cc[rr * 4 + 0] * inv, cc[rr * 4 + 1] * inv);
      const unsigned u1 = pack_bf16(cc[rr * 4 + 2] * inv, cc[rr * 4 + 3] * inv);
      *(uint2*)(cb + l31 * 72 + mg2 * 32 + 4 * hi + 8 * rr) = uint2{u0, u1};
    }
  }
  __syncthreads();
  const __hip_bfloat16* crd =
      (const __hip_bfloat16*)(smem + w * 4608) + (l >> 1) * 72 + (l & 1) * 8;
  __hip_bfloat16* gout =
      ctx + ((size_t)b * NS + q0 + (l >> 1)) * ND + h * NDH + (l & 1) * 8;
#pragma unroll
  for (int i = 0; i < 4; ++i)
    *(short8*)(gout + i * 16) = *(const short8*)(crd + i * 16);
#undef STAGE
}

// ---------------- MFMA GEMM (output proj): f32 out ------------------------
__global__ __launch_bounds__(256) void gemm_bt_mfma_kernel(
    const __hip_bfloat16* __restrict__ A, const __hip_bfloat16* __restrict__ Bt,
    const float* __restrict__ bias, float* __restrict__ Cout,
    int M, int N, int K) {
  __shared__ __hip_bfloat16 As[128 * 32];
  __shared__ __hip_bfloat16 Bs[64 * 32];
  const int tid = threadIdx.x;
  const int w = tid >> 6, l = tid & 63;
  const int lk = l & 15, lt = l >> 4;
  const int m0 = blockIdx.y * 128, n0 = blockIdx.x * 64;
  const int wr = w >> 1, wc = w & 1;

  f32x4 acc[4][2] = {};

  const int arow = w * 32 + (l >> 2);
  const int acol = (l & 3) * 8;
  const __hip_bfloat16* aptr = A + (size_t)(m0 + arow) * K + acol;
  const int brow = w * 16 + (l >> 2);
  const __hip_bfloat16* bptr = Bt + (size_t)(n0 + brow) * K + acol;
  __hip_bfloat16* asb = As + w * 1024;
  __hip_bfloat16* bsb = Bs + w * 512;

  for (int k0 = 0; k0 < K; k0 += 32) {
    __syncthreads();
    async_ld16(aptr + k0, asb);
    async_ld16(aptr + (size_t)16 * K + k0, asb + 512);
    async_ld16(bptr + k0, bsb);
    __syncthreads();

    short8 af[4], bf[2];
#pragma unroll
    for (int m = 0; m < 4; ++m)
      af[m] = *(const short8*)(As + (wr * 64 + m * 16 + lk) * 32 + lt * 8);
#pragma unroll
    for (int n = 0; n < 2; ++n)
      bf[n] = *(const short8*)(Bs + (wc * 32 + n * 16 + lk) * 32 + lt * 8);
#pragma unroll
    for (int m = 0; m < 4; ++m)
#pragma unroll
      for (int n = 0; n < 2; ++n)
        acc[m][n] =
            __builtin_amdgcn_mfma_f32_16x16x32_bf16(af[m], bf[n], acc[m][n], 0, 0, 0);
  }

#pragma unroll
  for (int n = 0; n < 2; ++n) {
    const int col = n0 + wc * 32 + n * 16 + lk;
    const float bb = bias[col];
#pragma unroll
    for (int m = 0; m < 4; ++m) {
      const int row = m0 + wr * 64 + m * 16 + lt * 4;
#pragma unroll
      for (int r = 0; r < 4; ++r)
        Cout[(size_t)(row + r) * N + col] = acc[m][n][r] + bb;
    }
  }
}

extern "C" void kernel_launch(void* const* d_in, const int* in_sizes, int n_in,
                              void* d_out, int out_size, void* d_ws, size_t ws_size,
                              hipStream_t stream) {
  const float* x    = (const float*)d_in[0];
  const float* mask = (const float*)d_in[1];
  const float* wq   = (const float*)d_in[2];
  const float* bq   = (const float*)d_in[3];
  const float* wk   = (const float*)d_in[4];
  const float* bk   = (const float*)d_in[5];
  const float* wv   = (const float*)d_in[6];
  const float* bv   = (const float*)d_in[7];
  const float* wo   = (const float*)d_in[8];
  const float* bo   = (const float*)d_in[9];
  float* out = (float*)d_out;

  const size_t mat = (size_t)NM * ND;
  const size_t wmat = (size_t)ND * ND;
  __hip_bfloat16* xb    = (__hip_bfloat16*)d_ws;
  __hip_bfloat16* WtAll = xb + mat;
  __hip_bfloat16* Qw    = WtAll + 4 * wmat;
  __hip_bfloat16* Kw    = Qw + mat;
  __hip_bfloat16* Vtw   = Kw + mat;
  __hip_bfloat16* Cw    = Vtw + mat;
  float* mpg            = (float*)(Cw + mat);   // 8192 floats, 32KB

  convert_bf16_kernel<<<(NM * ND / 8 + 255) / 256, 256, 0, stream>>>(
      x, xb, NM * ND / 8);
  mask_perm_kernel<<<NM / 256, 256, 0, stream>>>(mask, mpg);
  transpose_w_kernel<<<dim3(ND / 64, ND / 64, 4), 256, 0, stream>>>(
      wq, wk, wv, wo, WtAll);

  qkv_gemm_kernel<<<dim3(3 * ND / 64, NM / 128), 256, 0, stream>>>(
      xb, WtAll, bq, bk, bv, Qw, Kw, Vtw);

  mha_mfma32_kernel<<<dim3(NS / 128, NH, NB), 256, 0, stream>>>(
      Qw, Kw, Vtw, mpg, Cw);

  gemm_bt_mfma_kernel<<<dim3(ND / 64, NM / 128), 256, 0, stream>>>(
      Cw, WtAll + 3 * wmat, bo, out, NM, ND, ND);
}

// Round 8
// 209.470 us; speedup vs baseline: 1.0796x; 1.0460x over previous
//
#include <hip/hip_runtime.h>
#include <hip/hip_bf16.h>

#define NB 4
#define NS 2048
#define ND 768
#define NH 12
#define NDH 64
#define NM (NB * NS)  // 8192

// fold 1/sqrt(64) * log2(e) into Q so softmax = exp2(s); mask pre-scaled
#define QSCALE 0.1803368867f
#define MSCALE (-1.442695041e9f)

typedef __attribute__((ext_vector_type(8))) short short8;    // 8 x bf16
typedef __attribute__((ext_vector_type(4))) float f32x4;
typedef __attribute__((ext_vector_type(16))) float f32x16;

__device__ __forceinline__ void async_ld16(const void* g, void* l) {
  __builtin_amdgcn_global_load_lds(
      (const __attribute__((address_space(1))) void*)g,
      (__attribute__((address_space(3))) void*)l, 16, 0, 0);
}

// plain scalar packing — compiler pairs these into v_cvt_pk_bf16_f32
__device__ __forceinline__ unsigned pack_bf16(float a, float b) {
  return ((unsigned)__bfloat16_as_ushort(__float2bfloat16(b)) << 16) |
         (unsigned)__bfloat16_as_ushort(__float2bfloat16(a));
}

// VALU cross-half exchange: a <- [a.lo | partner.b.lo], b <- [partner.a.hi | b.hi]
__device__ __forceinline__ void permlane_swap(unsigned& a, unsigned& b) {
  asm("v_permlane32_swap_b32 %0, %1" : "+v"(a), "+v"(b));
}

// ---------------- f32 -> bf16 convert (vectorized, 8/thread) --------------
__global__ __launch_bounds__(256) void convert_bf16_kernel(
    const float* __restrict__ in, __hip_bfloat16* __restrict__ out, int n8) {
  const int i = blockIdx.x * 256 + threadIdx.x;
  if (i >= n8) return;
  const float4 a = ((const float4*)in)[i * 2];
  const float4 b = ((const float4*)in)[i * 2 + 1];
  short8 v;
  __hip_bfloat16* p = (__hip_bfloat16*)&v;
  p[0] = __float2bfloat16(a.x); p[1] = __float2bfloat16(a.y);
  p[2] = __float2bfloat16(a.z); p[3] = __float2bfloat16(a.w);
  p[4] = __float2bfloat16(b.x); p[5] = __float2bfloat16(b.y);
  p[6] = __float2bfloat16(b.z); p[7] = __float2bfloat16(b.w);
  ((short8*)out)[i] = v;
}

// ------- mask precompute: crow-permuted + scaled + per-(b,tile) bitmap ----
__global__ __launch_bounds__(256) void mask_perm_kernel(
    const float* __restrict__ mask, float* __restrict__ mperm_g,
    unsigned* __restrict__ mbits) {
  const int idx = blockIdx.x * 256 + threadIdx.x;  // 0..8191
  const int b = idx >> 11;
  const int sb = idx & 2047;
  const int tile = sb >> 6, slot = sb & 63;
  const int g = slot >> 5, hh = (slot >> 4) & 1, r = slot & 15;
  const int key = tile * 64 + g * 32 + 4 * hh + (r & 3) + 8 * (r >> 2);
  const float v = mask[b * NS + key];
  mperm_g[idx] = v * MSCALE;
  if (v != 0.f) atomicOr(&mbits[b], 1u << tile);
}

// ------- weight transpose+convert: W[K][N] f32 -> Wt[N][K] bf16 -----------
__global__ __launch_bounds__(256) void transpose_w_kernel(
    const float* __restrict__ w0, const float* __restrict__ w1,
    const float* __restrict__ w2, const float* __restrict__ w3,
    __hip_bfloat16* __restrict__ WtAll) {
  __shared__ __hip_bfloat16 tile[64][66];
  const float* src = blockIdx.z == 0 ? w0 : blockIdx.z == 1 ? w1
                   : blockIdx.z == 2 ? w2 : w3;
  __hip_bfloat16* dst = WtAll + (size_t)blockIdx.z * ND * ND;
  const int kk0 = blockIdx.y * 64, nn0 = blockIdx.x * 64;
  const int t = threadIdx.x;
#pragma unroll
  for (int p = 0; p < 4; ++p) {
    const int idx = p * 256 + t;
    const int k = idx >> 4;
    const int c = (idx & 15) * 4;
    const float4 v = *(const float4*)(src + (size_t)(kk0 + k) * ND + nn0 + c);
    __hip_bfloat162* tp = (__hip_bfloat162*)&tile[k][c];
    tp[0] = __hip_bfloat162{__float2bfloat16(v.x), __float2bfloat16(v.y)};
    tp[1] = __hip_bfloat162{__float2bfloat16(v.z), __float2bfloat16(v.w)};
  }
  __syncthreads();
#pragma unroll
  for (int p = 0; p < 2; ++p) {
    const int idx = p * 256 + t;
    const int n = idx >> 3;
    const int kb = (idx & 7) * 8;
    short8 v;
    __hip_bfloat16* pv = (__hip_bfloat16*)&v;
#pragma unroll
    for (int j = 0; j < 8; ++j) pv[j] = tile[kb + j][n];
    *(short8*)(dst + (size_t)(nn0 + n) * ND + kk0 + kb) = v;
  }
}

// ------- fused QKV GEMM: 128x128 tile, BK=32, 4 waves (64x64 each) --------
__global__ __launch_bounds__(256) void qkv_gemm_kernel(
    const __hip_bfloat16* __restrict__ A,
    const __hip_bfloat16* __restrict__ Bt,
    const float* __restrict__ bq, const float* __restrict__ bk,
    const float* __restrict__ bv,
    __hip_bfloat16* __restrict__ Qw, __hip_bfloat16* __restrict__ Kw,
    __hip_bfloat16* __restrict__ Vt) {
  __shared__ __hip_bfloat16 As[128 * 32];  // [row][k] 8KB
  __shared__ __hip_bfloat16 Bs[128 * 32];  // [col][k] 8KB
  const int K = ND;
  const int tid = threadIdx.x;
  const int w = tid >> 6, l = tid & 63;
  const int lk = l & 15, lt = l >> 4;
  const int m0 = blockIdx.y * 128, n0 = blockIdx.x * 128;
  const int wr = w >> 1, wc = w & 1;

  f32x4 acc[4][4] = {};

  const int arow = w * 32 + (l >> 2);   // +16 for second load
  const int acol = (l & 3) * 8;
  const __hip_bfloat16* aptr = A + (size_t)(m0 + arow) * K + acol;
  const __hip_bfloat16* bptr = Bt + (size_t)(n0 + arow) * K + acol;
  __hip_bfloat16* asb = As + w * 1024;
  __hip_bfloat16* bsb = Bs + w * 1024;

  for (int k0 = 0; k0 < K; k0 += 32) {
    __syncthreads();
    async_ld16(aptr + k0, asb);
    async_ld16(aptr + (size_t)16 * K + k0, asb + 512);
    async_ld16(bptr + k0, bsb);
    async_ld16(bptr + (size_t)16 * K + k0, bsb + 512);
    __syncthreads();

    short8 af[4], bf[4];
#pragma unroll
    for (int m = 0; m < 4; ++m)
      af[m] = *(const short8*)(As + (wr * 64 + m * 16 + lk) * 32 + lt * 8);
#pragma unroll
    for (int n = 0; n < 4; ++n)
      bf[n] = *(const short8*)(Bs + (wc * 64 + n * 16 + lk) * 32 + lt * 8);
#pragma unroll
    for (int m = 0; m < 4; ++m)
#pragma unroll
      for (int n = 0; n < 4; ++n)
        acc[m][n] =
            __builtin_amdgcn_mfma_f32_16x16x32_bf16(af[m], bf[n], acc[m][n], 0, 0, 0);
  }

  const int mi = n0 / ND;          // 0=Q, 1=K, 2=V (768/128=6: no straddle)
  const int nbase = n0 - mi * ND;
  const float* bp = mi == 0 ? bq : mi == 1 ? bk : bv;
  const float oscale = (mi == 0) ? QSCALE : 1.f;

#pragma unroll
  for (int n = 0; n < 4; ++n) {
    const int col = nbase + wc * 64 + n * 16 + lk;
    const float bb = bp[col];
#pragma unroll
    for (int m = 0; m < 4; ++m) {
      const int row = m0 + wr * 64 + m * 16 + lt * 4;
#pragma unroll
      for (int r = 0; r < 4; ++r) {
        const float v = (acc[m][n][r] + bb) * oscale;
        if (mi < 2) {
          (mi ? Kw : Qw)[(size_t)(row + r) * ND + col] = __float2bfloat16(v);
        } else {
          const int mrow = row + r;
          const int bidx = mrow >> 11, s = mrow & 2047;
          const int hh = col >> 6, dh = col & 63;
          Vt[(((size_t)bidx * NH + hh) * NDH + dh) * NS + s] = __float2bfloat16(v);
        }
      }
    }
  }
}

// ---------------- MFMA-32x32 flash attention, register-resident P ---------
// LDS pipe diet: zero-reg C-init (mask via bitmap + rare additive path),
// permlane32_swap (VALU) instead of ds_bpermute. 16 ds_read_b128/tile.
__global__ __launch_bounds__(256) void mha_mfma32_kernel(
    const __hip_bfloat16* __restrict__ Qb, const __hip_bfloat16* __restrict__ Kb,
    const __hip_bfloat16* __restrict__ Vt, const float* __restrict__ mperm_g,
    const unsigned* __restrict__ maskbits, __hip_bfloat16* __restrict__ ctx) {
  // [0,24576): K bufs (3x8KB) | [24576,49152): V bufs
  __shared__ __align__(16) char smem[49152];
  char* KsB = smem;
  char* VsB = smem + 24576;

  const int b = blockIdx.z, h = blockIdx.y;
  const int tid = threadIdx.x;
  const int w = tid >> 6, l = tid & 63;
  const int l31 = l & 31, hi = l >> 5;
  const int q0 = blockIdx.x * 128 + w * 32;
  const unsigned mbitsb = maskbits[b];   // s_load, wave-uniform

  const __hip_bfloat16* qp = Qb + ((size_t)b * NS + q0 + l31) * ND + h * NDH;
  short8 qf[4];
#pragma unroll
  for (int ks = 0; ks < 4; ++ks)
    qf[ks] = *(const short8*)(qp + ks * 16 + hi * 8);

  f32x16 c0 = {}, c1 = {};
  const f32x16 z16 = {};
  float lpart = 0.f;

  const int srow = l >> 3, slot = l & 7;
  const int key1 = w * 8 + srow, key2 = key1 + 32;
  const __hip_bfloat16* kg1 =
      Kb + ((size_t)b * NS + key1) * ND + h * NDH + (slot ^ (key1 & 7)) * 8;
  const __hip_bfloat16* kg2 =
      Kb + ((size_t)b * NS + key2) * ND + h * NDH + (slot ^ (key2 & 7)) * 8;
  const __hip_bfloat16* vg1 =
      Vt + (((size_t)b * NH + h) * NDH + key1) * NS + (slot ^ (key1 & 7)) * 8;
  const __hip_bfloat16* vg2 =
      Vt + (((size_t)b * NH + h) * NDH + key2) * NS + (slot ^ (key2 & 7)) * 8;
  const int ldsoff = w * 1024;
  const float* mg = mperm_g + (size_t)b * NS;  // crow-permuted, pre-scaled

  // uniform 4 async loads per wave per stage (vmcnt accounting)
#define STAGE(buf, t)                                                        \
  {                                                                          \
    const size_t koff = (size_t)(t) * 64 * ND;                               \
    char* kd = KsB + (buf) * 8192 + ldsoff;                                  \
    char* vd = VsB + (buf) * 8192 + ldsoff;                                  \
    async_ld16(kg1 + koff, kd);                                              \
    async_ld16(kg2 + koff, kd + 4096);                                       \
    async_ld16(vg1 + (t) * 64, vd);                                          \
    async_ld16(vg2 + (t) * 64, vd + 4096);                                   \
  }

  const int swz = (l31 & 7) << 4;

  auto compute_tile = [&](int t, int cur2) {
    const int bufo = cur2 * 8192;
    // ---- QK^T, C starts from persistent zero regs (no init moves) ----
    f32x16 s0, s1;
#pragma unroll
    for (int ks = 0; ks < 4; ++ks) {
      const int off = (((ks << 5) | (hi << 4)) ^ swz);
      const short8 kf0 = *(const short8*)(KsB + bufo + (l31 << 7) + off);
      const short8 kf1 = *(const short8*)(KsB + bufo + ((32 + l31) << 7) + off);
      if (ks == 0) {
        s0 = __builtin_amdgcn_mfma_f32_32x32x16_bf16(kf0, qf[0], z16, 0, 0, 0);
        s1 = __builtin_amdgcn_mfma_f32_32x32x16_bf16(kf1, qf[0], z16, 0, 0, 0);
      } else {
        s0 = __builtin_amdgcn_mfma_f32_32x32x16_bf16(kf0, qf[ks], s0, 0, 0, 0);
        s1 = __builtin_amdgcn_mfma_f32_32x32x16_bf16(kf1, qf[ks], s1, 0, 0, 0);
      }
    }

    // ---- rare path: this tile has nonzero mask values (additive) ----
    if ((mbitsb >> t) & 1) {
      const float* mgt = mg + t * 64 + hi * 16;
#pragma unroll
      for (int r = 0; r < 16; ++r) {
        s0[r] += mgt[r];
        s1[r] += mgt[32 + r];
      }
    }

    // ---- softmax: p = exp2(s), native v_exp_f32 ----
#pragma unroll
    for (int r = 0; r < 16; ++r) {
      const float pv = exp2f(s0[r]);
      s0[r] = pv;
      lpart += pv;
    }
#pragma unroll
    for (int r = 0; r < 16; ++r) {
      const float pv = exp2f(s1[r]);
      s1[r] = pv;
      lpart += pv;
    }

    // ---- PV: P^T B-frags via pack + permlane32_swap (pure VALU) ----
#pragma unroll
    for (int ks = 0; ks < 4; ++ks) {
      const f32x16& S = (ks < 2) ? s0 : s1;
      const int r0 = (ks & 1) * 8;
      unsigned u0 = pack_bf16(S[r0 + 0], S[r0 + 1]);
      unsigned u1 = pack_bf16(S[r0 + 2], S[r0 + 3]);
      unsigned u2 = pack_bf16(S[r0 + 4], S[r0 + 5]);
      unsigned u3 = pack_bf16(S[r0 + 6], S[r0 + 7]);
      permlane_swap(u0, u2);
      permlane_swap(u1, u3);
      union { unsigned u[4]; short8 v; } pf = {{u0, u1, u2, u3}};
      const int off = (((ks << 5) | (hi << 4)) ^ swz);
      const short8 vf0 = *(const short8*)(VsB + bufo + (l31 << 7) + off);
      c0 = __builtin_amdgcn_mfma_f32_32x32x16_bf16(vf0, pf.v, c0, 0, 0, 0);
      const short8 vf1 = *(const short8*)(VsB + bufo + ((32 + l31) << 7) + off);
      c1 = __builtin_amdgcn_mfma_f32_32x32x16_bf16(vf1, pf.v, c1, 0, 0, 0);
    }
  };

  STAGE(0, 0);
  STAGE(1, 1);
  int cur = 0;
  for (int t = 0; t < 30; ++t) {
    // tile t's 4 loads done; tile t+1's 4 stay in flight across the barrier
    asm volatile("s_waitcnt vmcnt(4) lgkmcnt(0)" ::: "memory");
    __builtin_amdgcn_s_barrier();
    const int nb2 = (cur + 2 >= 3) ? cur - 1 : cur + 2;
    STAGE(nb2, t + 2);
    compute_tile(t, cur);
    cur = (cur + 1 >= 3) ? 0 : cur + 1;
  }
  asm volatile("s_waitcnt vmcnt(4) lgkmcnt(0)" ::: "memory");
  __builtin_amdgcn_s_barrier();
  compute_tile(30, cur);
  cur = (cur + 1 >= 3) ? 0 : cur + 1;
  asm volatile("s_waitcnt vmcnt(0) lgkmcnt(0)" ::: "memory");
  __builtin_amdgcn_s_barrier();
  compute_tile(31, cur);

  const float ltot = lpart + __shfl_xor(lpart, 32);
  const float inv = 1.f / ltot;

  // ---- epilogue: LDS bounce [32][76] (2-way-max banks) -> 16B stores ----
  __syncthreads();
  __hip_bfloat16* cb = (__hip_bfloat16*)(smem + w * 4864);  // 32*76*2 B
#pragma unroll
  for (int mg2 = 0; mg2 < 2; ++mg2) {
    const f32x16& cc = mg2 ? c1 : c0;
#pragma unroll
    for (int rr = 0; rr < 4; ++rr) {
      const unsigned u0 = pack_bf16(cc[rr * 4 + 0] * inv, cc[rr * 4 + 1] * inv);
      const unsigned u1 = pack_bf16(cc[rr * 4 + 2] * inv, cc[rr * 4 + 3] * inv);
      *(uint2*)(cb + l31 * 76 + mg2 * 32 + 4 * hi + 8 * rr) = uint2{u0, u1};
    }
  }
  __syncthreads();
  const __hip_bfloat16* crd =
      (const __hip_bfloat16*)(smem + w * 4864) + (l >> 1) * 76 + (l & 1) * 8;
  __hip_bfloat16* gout =
      ctx + ((size_t)b * NS + q0 + (l >> 1)) * ND + h * NDH + (l & 1) * 8;
#pragma unroll
  for (int i = 0; i < 4; ++i) {
    const uint2 a = *(const uint2*)(crd + i * 16);
    const uint2 b2 = *(const uint2*)(crd + i * 16 + 4);
    *(uint4*)(gout + i * 16) = uint4{a.x, a.y, b2.x, b2.y};
  }
#undef STAGE
}

// ---------------- MFMA GEMM (output proj): 128x64, f32 out ----------------
__global__ __launch_bounds__(256) void gemm_bt_mfma_kernel(
    const __hip_bfloat16* __restrict__ A, const __hip_bfloat16* __restrict__ Bt,
    const float* __restrict__ bias, float* __restrict__ Cout,
    int M, int N, int K) {
  __shared__ __hip_bfloat16 As[128 * 32];
  __shared__ __hip_bfloat16 Bs[64 * 32];
  const int tid = threadIdx.x;
  const int w = tid >> 6, l = tid & 63;
  const int lk = l & 15, lt = l >> 4;
  const int m0 = blockIdx.y * 128, n0 = blockIdx.x * 64;
  const int wr = w >> 1, wc = w & 1;

  f32x4 acc[4][2] = {};

  const int arow = w * 32 + (l >> 2);
  const int acol = (l & 3) * 8;
  const __hip_bfloat16* aptr = A + (size_t)(m0 + arow) * K + acol;
  const int brow = w * 16 + (l >> 2);
  const __hip_bfloat16* bptr = Bt + (size_t)(n0 + brow) * K + acol;
  __hip_bfloat16* asb = As + w * 1024;
  __hip_bfloat16* bsb = Bs + w * 512;

  for (int k0 = 0; k0 < K; k0 += 32) {
    __syncthreads();
    async_ld16(aptr + k0, asb);
    async_ld16(aptr + (size_t)16 * K + k0, asb + 512);
    async_ld16(bptr + k0, bsb);
    __syncthreads();

    short8 af[4], bf[2];
#pragma unroll
    for (int m = 0; m < 4; ++m)
      af[m] = *(const short8*)(As + (wr * 64 + m * 16 + lk) * 32 + lt * 8);
#pragma unroll
    for (int n = 0; n < 2; ++n)
      bf[n] = *(const short8*)(Bs + (wc * 32 + n * 16 + lk) * 32 + lt * 8);
#pragma unroll
    for (int m = 0; m < 4; ++m)
#pragma unroll
      for (int n = 0; n < 2; ++n)
        acc[m][n] =
            __builtin_amdgcn_mfma_f32_16x16x32_bf16(af[m], bf[n], acc[m][n], 0, 0, 0);
  }

#pragma unroll
  for (int n = 0; n < 2; ++n) {
    const int col = n0 + wc * 32 + n * 16 + lk;
    const float bb = bias[col];
#pragma unroll
    for (int m = 0; m < 4; ++m) {
      const int row = m0 + wr * 64 + m * 16 + lt * 4;
#pragma unroll
      for (int r = 0; r < 4; ++r)
        Cout[(size_t)(row + r) * N + col] = acc[m][n][r] + bb;
    }
  }
}

extern "C" void kernel_launch(void* const* d_in, const int* in_sizes, int n_in,
                              void* d_out, int out_size, void* d_ws, size_t ws_size,
                              hipStream_t stream) {
  const float* x    = (const float*)d_in[0];
  const float* mask = (const float*)d_in[1];
  const float* wq   = (const float*)d_in[2];
  const float* bq   = (const float*)d_in[3];
  const float* wk   = (const float*)d_in[4];
  const float* bk   = (const float*)d_in[5];
  const float* wv   = (const float*)d_in[6];
  const float* bv   = (const float*)d_in[7];
  const float* wo   = (const float*)d_in[8];
  const float* bo   = (const float*)d_in[9];
  float* out = (float*)d_out;

  const size_t mat = (size_t)NM * ND;
  const size_t wmat = (size_t)ND * ND;
  __hip_bfloat16* xb    = (__hip_bfloat16*)d_ws;
  __hip_bfloat16* WtAll = xb + mat;
  __hip_bfloat16* Qw    = WtAll + 4 * wmat;
  __hip_bfloat16* Kw    = Qw + mat;
  __hip_bfloat16* Vtw   = Kw + mat;
  __hip_bfloat16* Cw    = Vtw + mat;
  float* mpg            = (float*)(Cw + mat);   // 8192 floats
  unsigned* mbits       = (unsigned*)(mpg + NM);  // 4 uints

  convert_bf16_kernel<<<(NM * ND / 8 + 255) / 256, 256, 0, stream>>>(
      x, xb, NM * ND / 8);
  hipMemsetAsync(mbits, 0, NB * sizeof(unsigned), stream);
  mask_perm_kernel<<<NM / 256, 256, 0, stream>>>(mask, mpg, mbits);
  transpose_w_kernel<<<dim3(ND / 64, ND / 64, 4), 256, 0, stream>>>(
      wq, wk, wv, wo, WtAll);

  qkv_gemm_kernel<<<dim3(3 * ND / 128, NM / 128), 256, 0, stream>>>(
      xb, WtAll, bq, bk, bv, Qw, Kw, Vtw);

  mha_mfma32_kernel<<<dim3(NS / 128, NH, NB), 256, 0, stream>>>(
      Qw, Kw, Vtw, mpg, mbits, Cw);

  gemm_bt_mfma_kernel<<<dim3(ND / 64, NM / 128), 256, 0, stream>>>(
      Cw, WtAll + 3 * wmat, bo, out, NM, ND, ND);
}

// Round 9
// 190.086 us; speedup vs baseline: 1.1897x; 1.1020x over previous
//
#include <hip/hip_runtime.h>
#include <hip/hip_bf16.h>

#define NB 4
#define NS 2048
#define ND 768
#define NH 12
#define NDH 64
#define NM (NB * NS)  // 8192

// fold 1/sqrt(64) * log2(e) into Q so softmax = exp2(s); mask pre-scaled
#define QSCALE 0.1803368867f
#define MSCALE (-1.442695041e9f)

typedef __attribute__((ext_vector_type(8))) short short8;    // 8 x bf16
typedef __attribute__((ext_vector_type(4))) float f32x4;
typedef __attribute__((ext_vector_type(16))) float f32x16;

__device__ __forceinline__ void async_ld16(const void* g, void* l) {
  __builtin_amdgcn_global_load_lds(
      (const __attribute__((address_space(1))) void*)g,
      (__attribute__((address_space(3))) void*)l, 16, 0, 0);
}

// plain scalar packing — compiler pairs these into v_cvt_pk_bf16_f32
__device__ __forceinline__ unsigned pack_bf16(float a, float b) {
  return ((unsigned)__bfloat16_as_ushort(__float2bfloat16(b)) << 16) |
         (unsigned)__bfloat16_as_ushort(__float2bfloat16(a));
}

// VALU cross-half exchange
__device__ __forceinline__ void permlane_swap(unsigned& a, unsigned& b) {
  asm("v_permlane32_swap_b32 %0, %1" : "+v"(a), "+v"(b));
}

// raw v_exp_f32: exp2 with flush-to-zero for large-negative (exact for mask)
__device__ __forceinline__ float fast_exp2(float x) {
  float r;
  asm("v_exp_f32 %0, %1" : "=v"(r) : "v"(x));
  return r;
}

// ---------------- f32 -> bf16 convert (vectorized, 8/thread) --------------
__global__ __launch_bounds__(256) void convert_bf16_kernel(
    const float* __restrict__ in, __hip_bfloat16* __restrict__ out, int n8) {
  const int i = blockIdx.x * 256 + threadIdx.x;
  if (i >= n8) return;
  const float4 a = ((const float4*)in)[i * 2];
  const float4 b = ((const float4*)in)[i * 2 + 1];
  short8 v;
  __hip_bfloat16* p = (__hip_bfloat16*)&v;
  p[0] = __float2bfloat16(a.x); p[1] = __float2bfloat16(a.y);
  p[2] = __float2bfloat16(a.z); p[3] = __float2bfloat16(a.w);
  p[4] = __float2bfloat16(b.x); p[5] = __float2bfloat16(b.y);
  p[6] = __float2bfloat16(b.z); p[7] = __float2bfloat16(b.w);
  ((short8*)out)[i] = v;
}

// ------- mask precompute: crow-permuted + scaled + per-(b,tile) bitmap ----
__global__ __launch_bounds__(256) void mask_perm_kernel(
    const float* __restrict__ mask, float* __restrict__ mperm_g,
    unsigned* __restrict__ mbits) {
  const int idx = blockIdx.x * 256 + threadIdx.x;  // 0..8191
  const int b = idx >> 11;
  const int sb = idx & 2047;
  const int tile = sb >> 6, slot = sb & 63;
  const int g = slot >> 5, hh = (slot >> 4) & 1, r = slot & 15;
  const int key = tile * 64 + g * 32 + 4 * hh + (r & 3) + 8 * (r >> 2);
  const float v = mask[b * NS + key];
  mperm_g[idx] = v * MSCALE;
  if (v != 0.f) atomicOr(&mbits[b], 1u << tile);
}

// ------- weight transpose+convert: W[K][N] f32 -> Wt[N][K] bf16 -----------
__global__ __launch_bounds__(256) void transpose_w_kernel(
    const float* __restrict__ w0, const float* __restrict__ w1,
    const float* __restrict__ w2, const float* __restrict__ w3,
    __hip_bfloat16* __restrict__ WtAll) {
  __shared__ __hip_bfloat16 tile[64][66];
  const float* src = blockIdx.z == 0 ? w0 : blockIdx.z == 1 ? w1
                   : blockIdx.z == 2 ? w2 : w3;
  __hip_bfloat16* dst = WtAll + (size_t)blockIdx.z * ND * ND;
  const int kk0 = blockIdx.y * 64, nn0 = blockIdx.x * 64;
  const int t = threadIdx.x;
#pragma unroll
  for (int p = 0; p < 4; ++p) {
    const int idx = p * 256 + t;
    const int k = idx >> 4;
    const int c = (idx & 15) * 4;
    const float4 v = *(const float4*)(src + (size_t)(kk0 + k) * ND + nn0 + c);
    __hip_bfloat162* tp = (__hip_bfloat162*)&tile[k][c];
    tp[0] = __hip_bfloat162{__float2bfloat16(v.x), __float2bfloat16(v.y)};
    tp[1] = __hip_bfloat162{__float2bfloat16(v.z), __float2bfloat16(v.w)};
  }
  __syncthreads();
#pragma unroll
  for (int p = 0; p < 2; ++p) {
    const int idx = p * 256 + t;
    const int n = idx >> 3;
    const int kb = (idx & 7) * 8;
    short8 v;
    __hip_bfloat16* pv = (__hip_bfloat16*)&v;
#pragma unroll
    for (int j = 0; j < 8; ++j) pv[j] = tile[kb + j][n];
    *(short8*)(dst + (size_t)(nn0 + n) * ND + kk0 + kb) = v;
  }
}

// ------- fused QKV GEMM: 128x128 tile, BK=32, 4 waves (64x64 each) --------
__global__ __launch_bounds__(256) void qkv_gemm_kernel(
    const __hip_bfloat16* __restrict__ A,
    const __hip_bfloat16* __restrict__ Bt,
    const float* __restrict__ bq, const float* __restrict__ bk,
    const float* __restrict__ bv,
    __hip_bfloat16* __restrict__ Qw, __hip_bfloat16* __restrict__ Kw,
    __hip_bfloat16* __restrict__ Vt) {
  __shared__ __hip_bfloat16 As[128 * 32];  // [row][k] 8KB
  __shared__ __hip_bfloat16 Bs[128 * 32];  // [col][k] 8KB
  const int K = ND;
  const int tid = threadIdx.x;
  const int w = tid >> 6, l = tid & 63;
  const int lk = l & 15, lt = l >> 4;
  const int m0 = blockIdx.y * 128, n0 = blockIdx.x * 128;
  const int wr = w >> 1, wc = w & 1;

  f32x4 acc[4][4] = {};

  const int arow = w * 32 + (l >> 2);   // +16 for second load
  const int acol = (l & 3) * 8;
  const __hip_bfloat16* aptr = A + (size_t)(m0 + arow) * K + acol;
  const __hip_bfloat16* bptr = Bt + (size_t)(n0 + arow) * K + acol;
  __hip_bfloat16* asb = As + w * 1024;
  __hip_bfloat16* bsb = Bs + w * 1024;

  for (int k0 = 0; k0 < K; k0 += 32) {
    __syncthreads();
    async_ld16(aptr + k0, asb);
    async_ld16(aptr + (size_t)16 * K + k0, asb + 512);
    async_ld16(bptr + k0, bsb);
    async_ld16(bptr + (size_t)16 * K + k0, bsb + 512);
    __syncthreads();

    short8 af[4], bf[4];
#pragma unroll
    for (int m = 0; m < 4; ++m)
      af[m] = *(const short8*)(As + (wr * 64 + m * 16 + lk) * 32 + lt * 8);
#pragma unroll
    for (int n = 0; n < 4; ++n)
      bf[n] = *(const short8*)(Bs + (wc * 64 + n * 16 + lk) * 32 + lt * 8);
#pragma unroll
    for (int m = 0; m < 4; ++m)
#pragma unroll
      for (int n = 0; n < 4; ++n)
        acc[m][n] =
            __builtin_amdgcn_mfma_f32_16x16x32_bf16(af[m], bf[n], acc[m][n], 0, 0, 0);
  }

  const int mi = n0 / ND;          // 0=Q, 1=K, 2=V (768/128=6: no straddle)
  const int nbase = n0 - mi * ND;
  const float* bp = mi == 0 ? bq : mi == 1 ? bk : bv;
  const float oscale = (mi == 0) ? QSCALE : 1.f;

#pragma unroll
  for (int n = 0; n < 4; ++n) {
    const int col = nbase + wc * 64 + n * 16 + lk;
    const float bb = bp[col];
#pragma unroll
    for (int m = 0; m < 4; ++m) {
      const int row = m0 + wr * 64 + m * 16 + lt * 4;
#pragma unroll
      for (int r = 0; r < 4; ++r) {
        const float v = (acc[m][n][r] + bb) * oscale;
        if (mi < 2) {
          (mi ? Kw : Qw)[(size_t)(row + r) * ND + col] = __float2bfloat16(v);
        } else {
          const int mrow = row + r;
          const int bidx = mrow >> 11, s = mrow & 2047;
          const int hh = col >> 6, dh = col & 63;
          Vt[(((size_t)bidx * NH + hh) * NDH + dh) * NS + s] = __float2bfloat16(v);
        }
      }
    }
  }
}

// ---------------- MFMA-32x32 flash attention, register-resident P ---------
// XCD-swizzled block mapping: all q-tiles of one (b,h) co-resident on one
// XCD -> K/V stays in that XCD's L2 (3.1 MB working set < 4 MB).
// Double-buffered staging (32 KB LDS), one vmcnt(0)+barrier per tile.
__global__ __launch_bounds__(256) void mha_mfma32_kernel(
    const __hip_bfloat16* __restrict__ Qb, const __hip_bfloat16* __restrict__ Kb,
    const __hip_bfloat16* __restrict__ Vt, const float* __restrict__ mperm_g,
    const unsigned* __restrict__ maskbits, __hip_bfloat16* __restrict__ ctx) {
  // [0,16384): K bufs (2x8KB) | [16384,32768): V bufs
  __shared__ __align__(16) char smem[32768];
  char* KsB = smem;
  char* VsB = smem + 16384;

  // bijective XCD swizzle: physical p -> logical (p&7)*96 + (p>>3)
  const int p = blockIdx.x + 16 * (blockIdx.y + 12 * blockIdx.z);
  const int logical = (p & 7) * 96 + (p >> 3);
  const int lx = logical & 15;         // q-tile
  const int rest = logical >> 4;       // 0..47
  const int h = rest % 12;
  const int b = rest / 12;

  const int tid = threadIdx.x;
  const int w = tid >> 6, l = tid & 63;
  const int l31 = l & 31, hi = l >> 5;
  const int q0 = lx * 128 + w * 32;
  const unsigned mbitsb = maskbits[b];   // s_load, wave-uniform

  const __hip_bfloat16* qp = Qb + ((size_t)b * NS + q0 + l31) * ND + h * NDH;
  short8 qf[4];
#pragma unroll
  for (int ks = 0; ks < 4; ++ks)
    qf[ks] = *(const short8*)(qp + ks * 16 + hi * 8);

  f32x16 c0 = {}, c1 = {};
  const f32x16 z16 = {};
  float lpart = 0.f;

  const int srow = l >> 3, slot = l & 7;
  const int key1 = w * 8 + srow, key2 = key1 + 32;
  const __hip_bfloat16* kg1 =
      Kb + ((size_t)b * NS + key1) * ND + h * NDH + (slot ^ (key1 & 7)) * 8;
  const __hip_bfloat16* kg2 =
      Kb + ((size_t)b * NS + key2) * ND + h * NDH + (slot ^ (key2 & 7)) * 8;
  const __hip_bfloat16* vg1 =
      Vt + (((size_t)b * NH + h) * NDH + key1) * NS + (slot ^ (key1 & 7)) * 8;
  const __hip_bfloat16* vg2 =
      Vt + (((size_t)b * NH + h) * NDH + key2) * NS + (slot ^ (key2 & 7)) * 8;
  const int ldsoff = w * 1024;
  const float* mg = mperm_g + (size_t)b * NS;  // crow-permuted, pre-scaled

  // uniform 4 async loads per wave per stage (vmcnt accounting)
#define STAGE(buf, t)                                                        \
  {                                                                          \
    const size_t koff = (size_t)(t) * 64 * ND;                               \
    char* kd = KsB + (buf) * 8192 + ldsoff;                                  \
    char* vd = VsB + (buf) * 8192 + ldsoff;                                  \
    async_ld16(kg1 + koff, kd);                                              \
    async_ld16(kg2 + koff, kd + 4096);                                       \
    async_ld16(vg1 + (t) * 64, vd);                                          \
    async_ld16(vg2 + (t) * 64, vd + 4096);                                   \
  }

  const int swz = (l31 & 7) << 4;

  auto compute_tile = [&](int t, int cur2) {
    const int bufo = cur2 * 8192;
    // ---- QK^T, C starts from persistent zero regs ----
    f32x16 s0, s1;
#pragma unroll
    for (int ks = 0; ks < 4; ++ks) {
      const int off = (((ks << 5) | (hi << 4)) ^ swz);
      const short8 kf0 = *(const short8*)(KsB + bufo + (l31 << 7) + off);
      const short8 kf1 = *(const short8*)(KsB + bufo + ((32 + l31) << 7) + off);
      if (ks == 0) {
        s0 = __builtin_amdgcn_mfma_f32_32x32x16_bf16(kf0, qf[0], z16, 0, 0, 0);
        s1 = __builtin_amdgcn_mfma_f32_32x32x16_bf16(kf1, qf[0], z16, 0, 0, 0);
      } else {
        s0 = __builtin_amdgcn_mfma_f32_32x32x16_bf16(kf0, qf[ks], s0, 0, 0, 0);
        s1 = __builtin_amdgcn_mfma_f32_32x32x16_bf16(kf1, qf[ks], s1, 0, 0, 0);
      }
    }

    // ---- rare path: this tile has nonzero mask values (additive) ----
    if ((mbitsb >> t) & 1) {
      const float* mgt = mg + t * 64 + hi * 16;
#pragma unroll
      for (int r = 0; r < 16; ++r) {
        s0[r] += mgt[r];
        s1[r] += mgt[32 + r];
      }
    }

    // ---- softmax: p = exp2(s), raw v_exp_f32 ----
#pragma unroll
    for (int r = 0; r < 16; ++r) {
      const float pv = fast_exp2(s0[r]);
      s0[r] = pv;
      lpart += pv;
    }
#pragma unroll
    for (int r = 0; r < 16; ++r) {
      const float pv = fast_exp2(s1[r]);
      s1[r] = pv;
      lpart += pv;
    }

    // ---- PV: P^T B-frags via pack + permlane32_swap (pure VALU) ----
#pragma unroll
    for (int ks = 0; ks < 4; ++ks) {
      const f32x16& S = (ks < 2) ? s0 : s1;
      const int r0 = (ks & 1) * 8;
      unsigned u0 = pack_bf16(S[r0 + 0], S[r0 + 1]);
      unsigned u1 = pack_bf16(S[r0 + 2], S[r0 + 3]);
      unsigned u2 = pack_bf16(S[r0 + 4], S[r0 + 5]);
      unsigned u3 = pack_bf16(S[r0 + 6], S[r0 + 7]);
      permlane_swap(u0, u2);
      permlane_swap(u1, u3);
      union { unsigned u[4]; short8 v; } pf = {{u0, u1, u2, u3}};
      const int off = (((ks << 5) | (hi << 4)) ^ swz);
      const short8 vf0 = *(const short8*)(VsB + bufo + (l31 << 7) + off);
      c0 = __builtin_amdgcn_mfma_f32_32x32x16_bf16(vf0, pf.v, c0, 0, 0, 0);
      const short8 vf1 = *(const short8*)(VsB + bufo + ((32 + l31) << 7) + off);
      c1 = __builtin_amdgcn_mfma_f32_32x32x16_bf16(vf1, pf.v, c1, 0, 0, 0);
    }
  };

  STAGE(0, 0);
  for (int t = 0; t < 32; ++t) {
    // tile t's 4 loads done; this wave's ds reads retired; all waves synced
    // (so buf (t+1)&1, last read in compute(t-1), is free to restage)
    asm volatile("s_waitcnt vmcnt(0) lgkmcnt(0)" ::: "memory");
    __builtin_amdgcn_s_barrier();
    if (t + 1 < 32) STAGE((t + 1) & 1, t + 1);
    compute_tile(t, t & 1);
  }

  const float ltot = lpart + __shfl_xor(lpart, 32);
  const float inv = 1.f / ltot;

  // ---- epilogue: LDS bounce [32][76] -> 16B stores ----
  __syncthreads();
  __hip_bfloat16* cb = (__hip_bfloat16*)(smem + w * 4864);  // 32*76*2 B
#pragma unroll
  for (int mg2 = 0; mg2 < 2; ++mg2) {
    const f32x16& cc = mg2 ? c1 : c0;
#pragma unroll
    for (int rr = 0; rr < 4; ++rr) {
      const unsigned u0 = pack_bf16(cc[rr * 4 + 0] * inv, cc[rr * 4 + 1] * inv);
      const unsigned u1 = pack_bf16(cc[rr * 4 + 2] * inv, cc[rr * 4 + 3] * inv);
      *(uint2*)(cb + l31 * 76 + mg2 * 32 + 4 * hi + 8 * rr) = uint2{u0, u1};
    }
  }
  __syncthreads();
  const __hip_bfloat16* crd =
      (const __hip_bfloat16*)(smem + w * 4864) + (l >> 1) * 76 + (l & 1) * 8;
  __hip_bfloat16* gout =
      ctx + ((size_t)b * NS + q0 + (l >> 1)) * ND + h * NDH + (l & 1) * 8;
#pragma unroll
  for (int i = 0; i < 4; ++i) {
    const uint2 a = *(const uint2*)(crd + i * 16);
    const uint2 b2 = *(const uint2*)(crd + i * 16 + 4);
    *(uint4*)(gout + i * 16) = uint4{a.x, a.y, b2.x, b2.y};
  }
#undef STAGE
}

// ---------------- MFMA GEMM (output proj): 128x64, f32 out ----------------
__global__ __launch_bounds__(256) void gemm_bt_mfma_kernel(
    const __hip_bfloat16* __restrict__ A, const __hip_bfloat16* __restrict__ Bt,
    const float* __restrict__ bias, float* __restrict__ Cout,
    int M, int N, int K) {
  __shared__ __hip_bfloat16 As[128 * 32];
  __shared__ __hip_bfloat16 Bs[64 * 32];
  const int tid = threadIdx.x;
  const int w = tid >> 6, l = tid & 63;
  const int lk = l & 15, lt = l >> 4;
  const int m0 = blockIdx.y * 128, n0 = blockIdx.x * 64;
  const int wr = w >> 1, wc = w & 1;

  f32x4 acc[4][2] = {};

  const int arow = w * 32 + (l >> 2);
  const int acol = (l & 3) * 8;
  const __hip_bfloat16* aptr = A + (size_t)(m0 + arow) * K + acol;
  const int brow = w * 16 + (l >> 2);
  const __hip_bfloat16* bptr = Bt + (size_t)(n0 + brow) * K + acol;
  __hip_bfloat16* asb = As + w * 1024;
  __hip_bfloat16* bsb = Bs + w * 512;

  for (int k0 = 0; k0 < K; k0 += 32) {
    __syncthreads();
    async_ld16(aptr + k0, asb);
    async_ld16(aptr + (size_t)16 * K + k0, asb + 512);
    async_ld16(bptr + k0, bsb);
    __syncthreads();

    short8 af[4], bf[2];
#pragma unroll
    for (int m = 0; m < 4; ++m)
      af[m] = *(const short8*)(As + (wr * 64 + m * 16 + lk) * 32 + lt * 8);
#pragma unroll
    for (int n = 0; n < 2; ++n)
      bf[n] = *(const short8*)(Bs + (wc * 32 + n * 16 + lk) * 32 + lt * 8);
#pragma unroll
    for (int m = 0; m < 4; ++m)
#pragma unroll
      for (int n = 0; n < 2; ++n)
        acc[m][n] =
            __builtin_amdgcn_mfma_f32_16x16x32_bf16(af[m], bf[n], acc[m][n], 0, 0, 0);
  }

#pragma unroll
  for (int n = 0; n < 2; ++n) {
    const int col = n0 + wc * 32 + n * 16 + lk;
    const float bb = bias[col];
#pragma unroll
    for (int m = 0; m < 4; ++m) {
      const int row = m0 + wr * 64 + m * 16 + lt * 4;
#pragma unroll
      for (int r = 0; r < 4; ++r)
        Cout[(size_t)(row + r) * N + col] = acc[m][n][r] + bb;
    }
  }
}

extern "C" void kernel_launch(void* const* d_in, const int* in_sizes, int n_in,
                              void* d_out, int out_size, void* d_ws, size_t ws_size,
                              hipStream_t stream) {
  const float* x    = (const float*)d_in[0];
  const float* mask = (const float*)d_in[1];
  const float* wq   = (const float*)d_in[2];
  const float* bq   = (const float*)d_in[3];
  const float* wk   = (const float*)d_in[4];
  const float* bk   = (const float*)d_in[5];
  const float* wv   = (const float*)d_in[6];
  const float* bv   = (const float*)d_in[7];
  const float* wo   = (const float*)d_in[8];
  const float* bo   = (const float*)d_in[9];
  float* out = (float*)d_out;

  const size_t mat = (size_t)NM * ND;
  const size_t wmat = (size_t)ND * ND;
  __hip_bfloat16* xb    = (__hip_bfloat16*)d_ws;
  __hip_bfloat16* WtAll = xb + mat;
  __hip_bfloat16* Qw    = WtAll + 4 * wmat;
  __hip_bfloat16* Kw    = Qw + mat;
  __hip_bfloat16* Vtw   = Kw + mat;
  __hip_bfloat16* Cw    = Vtw + mat;
  float* mpg            = (float*)(Cw + mat);   // 8192 floats
  unsigned* mbits       = (unsigned*)(mpg + NM);  // 4 uints

  convert_bf16_kernel<<<(NM * ND / 8 + 255) / 256, 256, 0, stream>>>(
      x, xb, NM * ND / 8);
  hipMemsetAsync(mbits, 0, NB * sizeof(unsigned), stream);
  mask_perm_kernel<<<NM / 256, 256, 0, stream>>>(mask, mpg, mbits);
  transpose_w_kernel<<<dim3(ND / 64, ND / 64, 4), 256, 0, stream>>>(
      wq, wk, wv, wo, WtAll);

  qkv_gemm_kernel<<<dim3(3 * ND / 128, NM / 128), 256, 0, stream>>>(
      xb, WtAll, bq, bk, bv, Qw, Kw, Vtw);

  mha_mfma32_kernel<<<dim3(NS / 128, NH, NB), 256, 0, stream>>>(
      Qw, Kw, Vtw, mpg, mbits, Cw);

  gemm_bt_mfma_kernel<<<dim3(ND / 64, NM / 128), 256, 0, stream>>>(
      Cw, WtAll + 3 * wmat, bo, out, NM, ND, ND);
}